// Round 3
// baseline (511.687 us; speedup 1.0000x reference)
//
#include <hip/hip_runtime.h>

#define NN      10000
#define IN_DIM  128
#define E_DIM   32
#define NH      4
#define DH      32
#define HD      128   // NH*DH
#define NE_     640000
#define OUT_DIM 32
#define SCAN_T  1024
#define CHUNK   10    // SCAN_T*CHUNK >= NN

typedef __attribute__((ext_vector_type(8))) short bf16x8;
typedef __attribute__((ext_vector_type(4))) float f32x4;

static __device__ __forceinline__ unsigned short f32_to_bf16_rne(float f) {
    unsigned u = __float_as_uint(f);
    return (unsigned short)((u + 0x7fffu + ((u >> 16) & 1u)) >> 16);
}
static __device__ __forceinline__ float bf16_bits_to_f32(unsigned short h) {
    return __uint_as_float(((unsigned)h) << 16);
}

// ---------------------------------------------------------------------------
// Kernel 1: per node n: Q,K to global; V to LDS; P[n,h,o] = V[n,h,:]@Wo_h[:,o]
// ---------------------------------------------------------------------------
__global__ __launch_bounds__(128) void qkvp_kernel(
    const float* __restrict__ x,
    const float* __restrict__ Wq, const float* __restrict__ bq,
    const float* __restrict__ Wk, const float* __restrict__ bk,
    const float* __restrict__ Wv, const float* __restrict__ bv,
    const float* __restrict__ Wo,
    float* __restrict__ Q, float* __restrict__ K, float* __restrict__ P)
{
    __shared__ float xs[IN_DIM];
    __shared__ float vs[HD];
    const int n = blockIdx.x;
    const int j = threadIdx.x;

    xs[j] = x[(size_t)n * IN_DIM + j];
    __syncthreads();

    float q = bq[j], k = bk[j], v = bv[j];
    #pragma unroll 8
    for (int i = 0; i < IN_DIM; ++i) {
        const float xv = xs[i];
        q = fmaf(xv, Wq[i * HD + j], q);
        k = fmaf(xv, Wk[i * HD + j], k);
        v = fmaf(xv, Wv[i * HD + j], v);
    }
    Q[(size_t)n * HD + j] = q;
    K[(size_t)n * HD + j] = k;
    vs[j] = v;
    __syncthreads();

    const int h = j >> 5, o = j & 31;
    float p = 0.f;
    #pragma unroll
    for (int d = 0; d < DH; ++d)
        p = fmaf(vs[h * DH + d], Wo[(h * DH + d) * OUT_DIM + o], p);
    P[(size_t)n * HD + j] = p;
}

// ---------------------------------------------------------------------------
// Kernel 1b: build pre-swizzled bf16 hi/lo MFMA A-fragments of We.
//   A-tile t (16 d-cols), lane l, elem j:  We[k = (l>>4)*8+j][d = t*16 + (l&15)]
//   frag[(t*64 + l)*8 + j]
// ---------------------------------------------------------------------------
__global__ __launch_bounds__(512) void wet_kernel(
    const float* __restrict__ We,
    unsigned short* __restrict__ frag_hi, unsigned short* __restrict__ frag_lo)
{
    const int tid = threadIdx.x;        // tid = t*64 + l
    const int l = tid & 63, t = tid >> 6;
    #pragma unroll
    for (int j = 0; j < 8; ++j) {
        const int k = (l >> 4) * 8 + j;
        const int d = t * 16 + (l & 15);
        const float w = We[k * HD + d];
        const unsigned short hi = f32_to_bf16_rne(w);
        const unsigned short lo = f32_to_bf16_rne(w - bf16_bits_to_f32(hi));
        frag_hi[tid * 8 + j] = hi;
        frag_lo[tid * 8 + j] = lo;
    }
}

// ---------------------------------------------------------------------------
// Kernel 2: ee4[e] = { ||ea[e]@We_h + be_h||^2 : h=0..3 }  via split-bf16 MFMA
//   D = A(We-tile: 16d x 32k) * B(ea-tile: 32k x 16edges)
//   C layout: n(edge) = lane&15, m(d) = (lane>>4)*4 + reg
// ---------------------------------------------------------------------------
__global__ __launch_bounds__(256) void ee_kernel(
    const float* __restrict__ ea,
    const unsigned short* __restrict__ frag_hi,
    const unsigned short* __restrict__ frag_lo,
    const float* __restrict__ be,
    float4* __restrict__ ee4)
{
    const int lane = threadIdx.x & 63;
    const int wave = threadIdx.x >> 6;
    const int base = blockIdx.x * 256 + wave * 64;   // 64 edges per wave

    // --- load + convert ea B-fragments for 4 tiles of 16 edges ---
    bf16x8 eahi[4], ealo[4];
    const int erow = lane & 15;
    const int kc = lane >> 4;          // k-chunk 0..3
    #pragma unroll
    for (int at = 0; at < 4; ++at) {
        const float* ar = ea + (size_t)(base + at * 16 + erow) * E_DIM + kc * 8;
        const float4 a0 = *reinterpret_cast<const float4*>(ar);
        const float4 a1 = *reinterpret_cast<const float4*>(ar + 4);
        float av[8] = {a0.x, a0.y, a0.z, a0.w, a1.x, a1.y, a1.z, a1.w};
        #pragma unroll
        for (int j = 0; j < 8; ++j) {
            const unsigned short hi = f32_to_bf16_rne(av[j]);
            const unsigned short lo = f32_to_bf16_rne(av[j] - bf16_bits_to_f32(hi));
            eahi[at][j] = (short)hi;
            ealo[at][j] = (short)lo;
        }
    }

    float part[4][NH] = {};   // [at][h] partial sum of ef^2 over this lane's d's

    #pragma unroll
    for (int t = 0; t < 8; ++t) {      // 8 d-tiles of 16
        const bf16x8 whi = *reinterpret_cast<const bf16x8*>(frag_hi + ((t * 64 + lane) << 3));
        const bf16x8 wlo = *reinterpret_cast<const bf16x8*>(frag_lo + ((t * 64 + lane) << 3));
        const float4 be4 = *reinterpret_cast<const float4*>(be + t * 16 + ((lane >> 4) << 2));
        #pragma unroll
        for (int at = 0; at < 4; ++at) {
            f32x4 acc = {0.f, 0.f, 0.f, 0.f};
            acc = __builtin_amdgcn_mfma_f32_16x16x32_bf16(whi, eahi[at], acc, 0, 0, 0);
            acc = __builtin_amdgcn_mfma_f32_16x16x32_bf16(whi, ealo[at], acc, 0, 0, 0);
            acc = __builtin_amdgcn_mfma_f32_16x16x32_bf16(wlo, eahi[at], acc, 0, 0, 0);
            const float e0 = acc[0] + be4.x, e1 = acc[1] + be4.y;
            const float e2 = acc[2] + be4.z, e3 = acc[3] + be4.w;
            part[at][t >> 1] += e0 * e0 + e1 * e1 + e2 * e2 + e3 * e3;
        }
    }

    #pragma unroll
    for (int at = 0; at < 4; ++at) {
        float4 r;
        float v0 = part[at][0]; v0 += __shfl_xor(v0, 16, 64); v0 += __shfl_xor(v0, 32, 64);
        float v1 = part[at][1]; v1 += __shfl_xor(v1, 16, 64); v1 += __shfl_xor(v1, 32, 64);
        float v2 = part[at][2]; v2 += __shfl_xor(v2, 16, 64); v2 += __shfl_xor(v2, 32, 64);
        float v3 = part[at][3]; v3 += __shfl_xor(v3, 16, 64); v3 += __shfl_xor(v3, 32, 64);
        r.x = v0; r.y = v1; r.z = v2; r.w = v3;
        if (lane < 16)
            ee4[base + at * 16 + lane] = r;
    }
}

// ---------------------------------------------------------------------------
// Kernel 3: degree histogram over src
// ---------------------------------------------------------------------------
__global__ __launch_bounds__(256) void hist_kernel(
    const int* __restrict__ ei, int* __restrict__ deg)
{
    const int e = blockIdx.x * blockDim.x + threadIdx.x;
    if (e >= NE_) return;
    atomicAdd(&deg[ei[e]], 1);
}

// ---------------------------------------------------------------------------
// Kernel 4: single-block exclusive scan of deg -> off, cur
// ---------------------------------------------------------------------------
__global__ __launch_bounds__(SCAN_T) void scan_kernel(
    const int* __restrict__ deg, int* __restrict__ off, int* __restrict__ cur)
{
    __shared__ int s[SCAN_T];
    const int t = threadIdx.x;
    const int base = t * CHUNK;
    int v[CHUNK];
    int sum = 0;
    #pragma unroll
    for (int i = 0; i < CHUNK; ++i) {
        const int idx = base + i;
        v[i] = (idx < NN) ? deg[idx] : 0;
        sum += v[i];
    }
    s[t] = sum;
    __syncthreads();
    for (int d = 1; d < SCAN_T; d <<= 1) {
        const int val = (t >= d) ? s[t - d] : 0;
        __syncthreads();
        s[t] += val;
        __syncthreads();
    }
    int run = s[t] - sum;   // exclusive prefix
    #pragma unroll
    for (int i = 0; i < CHUNK; ++i) {
        const int idx = base + i;
        if (idx < NN) { off[idx] = run; cur[idx] = run; run += v[i]; }
    }
}

// ---------------------------------------------------------------------------
// Kernel 5: per edge: qk gather-dot + ee -> softmax; payload into CSR slot.
//   payload = { bits(dst), a0, a1, a2 }   (a3 = 1 - a0 - a1 - a2)
// ---------------------------------------------------------------------------
__global__ __launch_bounds__(256) void score_kernel(
    const int*    __restrict__ ei,
    const float4* __restrict__ ee4,
    const float*  __restrict__ Q, const float* __restrict__ K,
    int* __restrict__ cur, float4* __restrict__ payload)
{
    const int e = blockIdx.x * blockDim.x + threadIdx.x;
    if (e >= NE_) return;

    const int src = ei[e];
    const int dst = ei[NE_ + e];
    const float4 ee = ee4[e];

    const float4* Qs = reinterpret_cast<const float4*>(Q + (size_t)src * HD);
    const float4* Kd = reinterpret_cast<const float4*>(K + (size_t)dst * HD);

    float sc[NH];
    const float eev[NH] = {ee.x, ee.y, ee.z, ee.w};
    #pragma unroll
    for (int h = 0; h < NH; ++h) {
        float qk = 0.f;
        #pragma unroll
        for (int i = 0; i < DH / 4; ++i) {
            const float4 q4 = Qs[h * 8 + i];
            const float4 k4 = Kd[h * 8 + i];
            qk = fmaf(q4.x, k4.x, fmaf(q4.y, k4.y,
                 fmaf(q4.z, k4.z, fmaf(q4.w, k4.w, qk))));
        }
        sc[h] = (qk + eev[h]) * 0.17677669529663687f;  // 1/sqrt(32)
    }

    const float m = fmaxf(fmaxf(sc[0], sc[1]), fmaxf(sc[2], sc[3]));
    float al[NH], ssum = 0.f;
    #pragma unroll
    for (int h = 0; h < NH; ++h) { al[h] = __expf(sc[h] - m); ssum += al[h]; }
    const float inv = 1.f / ssum;

    const int pos = atomicAdd(&cur[src], 1);
    payload[pos] = make_float4(__int_as_float(dst), al[0] * inv, al[1] * inv, al[2] * inv);
}

// ---------------------------------------------------------------------------
// Kernel 6: per node (256 thr = 8 groups of 32):
//   out[n,o] = (1/deg) * sum_seg sum_h al_h P[dst,h,o] + bo[o]
// ---------------------------------------------------------------------------
__global__ __launch_bounds__(256) void gather_kernel(
    const int* __restrict__ off, const int* __restrict__ deg,
    const float4* __restrict__ payload,
    const float* __restrict__ P, const float* __restrict__ bo,
    float* __restrict__ out)
{
    __shared__ float lds[8][OUT_DIM];
    const int n = blockIdx.x;
    const int d = deg[n];
    const int start = off[n];
    const int tid = threadIdx.x;
    const int g = tid >> 5, o = tid & 31;

    float acc = 0.f;
    for (int i = g; i < d; i += 8) {
        const float4 pay = payload[start + i];
        const int dst = __float_as_int(pay.x);
        const float a0 = pay.y, a1 = pay.z, a2 = pay.w;
        const float a3 = 1.f - a0 - a1 - a2;
        const float* __restrict__ Pr = P + (size_t)dst * HD;
        acc += a0 * Pr[o] + a1 * Pr[DH + o] + a2 * Pr[2 * DH + o] + a3 * Pr[3 * DH + o];
    }
    lds[g][o] = acc;
    __syncthreads();
    if (tid < 32) {
        float s = lds[0][o] + lds[1][o] + lds[2][o] + lds[3][o]
                + lds[4][o] + lds[5][o] + lds[6][o] + lds[7][o];
        out[(size_t)n * OUT_DIM + o] = (d > 0) ? (s / (float)d + bo[o]) : 0.f;
    }
}

extern "C" void kernel_launch(void* const* d_in, const int* in_sizes, int n_in,
                              void* d_out, int out_size, void* d_ws, size_t ws_size,
                              hipStream_t stream)
{
    const float* x   = (const float*)d_in[0];
    const int*   ei  = (const int*)  d_in[1];
    const float* ea  = (const float*)d_in[2];
    const float* Wq  = (const float*)d_in[3];
    const float* bq  = (const float*)d_in[4];
    const float* Wk  = (const float*)d_in[5];
    const float* bk  = (const float*)d_in[6];
    const float* Wv  = (const float*)d_in[7];
    const float* bv  = (const float*)d_in[8];
    const float* We  = (const float*)d_in[9];
    const float* be  = (const float*)d_in[10];
    const float* Wo  = (const float*)d_in[11];
    const float* bo  = (const float*)d_in[12];
    float* out = (float*)d_out;

    // workspace layout (16B-aligned chunks)
    float*  Q       = (float*)d_ws;                     // NN*HD
    float*  K       = Q + (size_t)NN * HD;              // NN*HD
    float*  P       = K + (size_t)NN * HD;              // NN*HD
    float4* ee4     = (float4*)(P + (size_t)NN * HD);   // NE_
    float4* payload = ee4 + NE_;                        // NE_
    unsigned short* frag_hi = (unsigned short*)(payload + NE_);  // 4096
    unsigned short* frag_lo = frag_hi + 8 * 64 * 8;              // 4096
    int* deg = (int*)(frag_lo + 8 * 64 * 8);            // NN
    int* off = deg + NN;                                // NN
    int* cur = off + NN;                                // NN

    hipMemsetAsync(deg, 0, NN * sizeof(int), stream);

    qkvp_kernel<<<NN, 128, 0, stream>>>(x, Wq, bq, Wk, bk, Wv, bv, Wo, Q, K, P);
    wet_kernel<<<1, 512, 0, stream>>>(We, frag_hi, frag_lo);
    ee_kernel<<<NE_ / 256, 256, 0, stream>>>(ea, frag_hi, frag_lo, be, ee4);
    hist_kernel<<<(NE_ + 255) / 256, 256, 0, stream>>>(ei, deg);
    scan_kernel<<<1, SCAN_T, 0, stream>>>(deg, off, cur);
    score_kernel<<<(NE_ + 255) / 256, 256, 0, stream>>>(ei, ee4, Q, K, cur, payload);
    gather_kernel<<<NN, 256, 0, stream>>>(off, deg, payload, P, bo, out);
}

// Round 4
// 262.925 us; speedup vs baseline: 1.9461x; 1.9461x over previous
//
#include <hip/hip_runtime.h>

#define NN      10000
#define IN_DIM  128
#define E_DIM   32
#define NH      4
#define DH      32
#define HD      128   // NH*DH
#define NE_     640000
#define OUT_DIM 32
#define SCAN_T  1024
#define CHUNK   10    // SCAN_T*CHUNK >= NN

typedef __attribute__((ext_vector_type(8))) short bf16x8;
typedef __attribute__((ext_vector_type(4))) float f32x4;

static __device__ __forceinline__ unsigned short f32_to_bf16_rne(float f) {
    unsigned u = __float_as_uint(f);
    return (unsigned short)((u + 0x7fffu + ((u >> 16) & 1u)) >> 16);
}
static __device__ __forceinline__ float bf16_bits_to_f32(unsigned short h) {
    return __uint_as_float(((unsigned)h) << 16);
}

// ---------------------------------------------------------------------------
// Kernel 1: per node n: Q,K to global; V to LDS; P[n,h,o] = V[n,h,:]@Wo_h[:,o]
// ---------------------------------------------------------------------------
__global__ __launch_bounds__(128) void qkvp_kernel(
    const float* __restrict__ x,
    const float* __restrict__ Wq, const float* __restrict__ bq,
    const float* __restrict__ Wk, const float* __restrict__ bk,
    const float* __restrict__ Wv, const float* __restrict__ bv,
    const float* __restrict__ Wo,
    float* __restrict__ Q, float* __restrict__ K, float* __restrict__ P)
{
    __shared__ float xs[IN_DIM];
    __shared__ float vs[HD];
    const int n = blockIdx.x;
    const int j = threadIdx.x;

    xs[j] = x[(size_t)n * IN_DIM + j];
    __syncthreads();

    float q = bq[j], k = bk[j], v = bv[j];
    #pragma unroll 8
    for (int i = 0; i < IN_DIM; ++i) {
        const float xv = xs[i];
        q = fmaf(xv, Wq[i * HD + j], q);
        k = fmaf(xv, Wk[i * HD + j], k);
        v = fmaf(xv, Wv[i * HD + j], v);
    }
    Q[(size_t)n * HD + j] = q;
    K[(size_t)n * HD + j] = k;
    vs[j] = v;
    __syncthreads();

    const int h = j >> 5, o = j & 31;
    float p = 0.f;
    #pragma unroll
    for (int d = 0; d < DH; ++d)
        p = fmaf(vs[h * DH + d], Wo[(h * DH + d) * OUT_DIM + o], p);
    P[(size_t)n * HD + j] = p;
}

// ---------------------------------------------------------------------------
// Kernel 1b: build pre-swizzled bf16 hi/lo MFMA A-fragments of We.
//   A-tile t (16 d-cols), lane l, elem j:  We[k = (l>>4)*8+j][d = t*16 + (l&15)]
// ---------------------------------------------------------------------------
__global__ __launch_bounds__(512) void wet_kernel(
    const float* __restrict__ We,
    unsigned short* __restrict__ frag_hi, unsigned short* __restrict__ frag_lo)
{
    const int tid = threadIdx.x;        // tid = t*64 + l
    const int l = tid & 63, t = tid >> 6;
    #pragma unroll
    for (int j = 0; j < 8; ++j) {
        const int k = (l >> 4) * 8 + j;
        const int d = t * 16 + (l & 15);
        const float w = We[k * HD + d];
        const unsigned short hi = f32_to_bf16_rne(w);
        const unsigned short lo = f32_to_bf16_rne(w - bf16_bits_to_f32(hi));
        frag_hi[tid * 8 + j] = hi;
        frag_lo[tid * 8 + j] = lo;
    }
}

// ---------------------------------------------------------------------------
// Kernel 2: degree histogram over src
// ---------------------------------------------------------------------------
__global__ __launch_bounds__(256) void hist_kernel(
    const int* __restrict__ ei, int* __restrict__ deg)
{
    const int e = blockIdx.x * blockDim.x + threadIdx.x;
    if (e >= NE_) return;
    atomicAdd(&deg[ei[e]], 1);
}

// ---------------------------------------------------------------------------
// Kernel 3: single-block exclusive scan of deg -> off, cur
// ---------------------------------------------------------------------------
__global__ __launch_bounds__(SCAN_T) void scan_kernel(
    const int* __restrict__ deg, int* __restrict__ off, int* __restrict__ cur)
{
    __shared__ int s[SCAN_T];
    const int t = threadIdx.x;
    const int base = t * CHUNK;
    int v[CHUNK];
    int sum = 0;
    #pragma unroll
    for (int i = 0; i < CHUNK; ++i) {
        const int idx = base + i;
        v[i] = (idx < NN) ? deg[idx] : 0;
        sum += v[i];
    }
    s[t] = sum;
    __syncthreads();
    for (int d = 1; d < SCAN_T; d <<= 1) {
        const int val = (t >= d) ? s[t - d] : 0;
        __syncthreads();
        s[t] += val;
        __syncthreads();
    }
    int run = s[t] - sum;   // exclusive prefix
    #pragma unroll
    for (int i = 0; i < CHUNK; ++i) {
        const int idx = base + i;
        if (idx < NN) { off[idx] = run; cur[idx] = run; run += v[i]; }
    }
}

// ---------------------------------------------------------------------------
// Kernel 4: ee via split-bf16 MFMA + CSR slot scatter.
//   per wave: 64 edges; tile at holds edges base+at*16+{0..15} in lanes 0..15.
//   epilogue: pos = atomicAdd(cur[src]); cdst[pos] = dst; cee[pos] = ee4.
// ---------------------------------------------------------------------------
__global__ __launch_bounds__(256) void ee_scatter_kernel(
    const float* __restrict__ ea,
    const unsigned short* __restrict__ frag_hi,
    const unsigned short* __restrict__ frag_lo,
    const float* __restrict__ be,
    const int* __restrict__ ei,
    int* __restrict__ cur, int* __restrict__ cdst, float4* __restrict__ cee)
{
    const int lane = threadIdx.x & 63;
    const int wave = threadIdx.x >> 6;
    const int base = blockIdx.x * 256 + wave * 64;   // 64 edges per wave

    // --- load + convert ea B-fragments for 4 tiles of 16 edges ---
    bf16x8 eahi[4], ealo[4];
    const int erow = lane & 15;
    const int kc = lane >> 4;          // k-chunk 0..3
    #pragma unroll
    for (int at = 0; at < 4; ++at) {
        const float* ar = ea + (size_t)(base + at * 16 + erow) * E_DIM + kc * 8;
        const float4 a0 = *reinterpret_cast<const float4*>(ar);
        const float4 a1 = *reinterpret_cast<const float4*>(ar + 4);
        float av[8] = {a0.x, a0.y, a0.z, a0.w, a1.x, a1.y, a1.z, a1.w};
        #pragma unroll
        for (int j = 0; j < 8; ++j) {
            const unsigned short hi = f32_to_bf16_rne(av[j]);
            const unsigned short lo = f32_to_bf16_rne(av[j] - bf16_bits_to_f32(hi));
            eahi[at][j] = (short)hi;
            ealo[at][j] = (short)lo;
        }
    }

    float part[4][NH] = {};   // [at][h] partial sum of ef^2 over this lane's d's

    #pragma unroll
    for (int t = 0; t < 8; ++t) {      // 8 d-tiles of 16
        const bf16x8 whi = *reinterpret_cast<const bf16x8*>(frag_hi + ((t * 64 + lane) << 3));
        const bf16x8 wlo = *reinterpret_cast<const bf16x8*>(frag_lo + ((t * 64 + lane) << 3));
        const float4 be4 = *reinterpret_cast<const float4*>(be + t * 16 + ((lane >> 4) << 2));
        #pragma unroll
        for (int at = 0; at < 4; ++at) {
            f32x4 acc = {0.f, 0.f, 0.f, 0.f};
            acc = __builtin_amdgcn_mfma_f32_16x16x32_bf16(whi, eahi[at], acc, 0, 0, 0);
            acc = __builtin_amdgcn_mfma_f32_16x16x32_bf16(whi, ealo[at], acc, 0, 0, 0);
            acc = __builtin_amdgcn_mfma_f32_16x16x32_bf16(wlo, eahi[at], acc, 0, 0, 0);
            const float e0 = acc[0] + be4.x, e1 = acc[1] + be4.y;
            const float e2 = acc[2] + be4.z, e3 = acc[3] + be4.w;
            part[at][t >> 1] += e0 * e0 + e1 * e1 + e2 * e2 + e3 * e3;
        }
    }

    #pragma unroll
    for (int at = 0; at < 4; ++at) {
        float v0 = part[at][0]; v0 += __shfl_xor(v0, 16, 64); v0 += __shfl_xor(v0, 32, 64);
        float v1 = part[at][1]; v1 += __shfl_xor(v1, 16, 64); v1 += __shfl_xor(v1, 32, 64);
        float v2 = part[at][2]; v2 += __shfl_xor(v2, 16, 64); v2 += __shfl_xor(v2, 32, 64);
        float v3 = part[at][3]; v3 += __shfl_xor(v3, 16, 64); v3 += __shfl_xor(v3, 32, 64);
        if (lane < 16) {
            const int e = base + at * 16 + lane;
            const int src = ei[e];
            const int dst = ei[NE_ + e];
            const int pos = atomicAdd(&cur[src], 1);
            cdst[pos] = dst;
            cee[pos] = make_float4(v0, v1, v2, v3);
        }
    }
}

// ---------------------------------------------------------------------------
// Kernel 5: fused score+softmax+aggregate, CSR order.
//   block = node n, 8 groups of 32 lanes; group processes one edge at a time.
//   lane o: qk partial over d=o, butterfly-reduce; softmax; acc += alpha.P[dst]
// ---------------------------------------------------------------------------
__global__ __launch_bounds__(256) void fused_gather_kernel(
    const int* __restrict__ off, const int* __restrict__ deg,
    const int* __restrict__ cdst, const float4* __restrict__ cee,
    const float* __restrict__ Q, const float* __restrict__ K,
    const float* __restrict__ P, const float* __restrict__ bo,
    float* __restrict__ out)
{
    __shared__ float red[8][OUT_DIM];
    const int n = blockIdx.x;
    const int d = deg[n];
    const int start = off[n];
    const int tid = threadIdx.x;
    const int g = tid >> 5, o = tid & 31;

    const float* __restrict__ Qr = Q + (size_t)n * HD;
    const float q0 = Qr[o], q1 = Qr[DH + o], q2 = Qr[2 * DH + o], q3 = Qr[3 * DH + o];

    float acc = 0.f;
    for (int i = g; i < d; i += 8) {
        const int idx = start + i;
        const int dst = cdst[idx];
        const float4 ee = cee[idx];
        const float* __restrict__ Kr = K + (size_t)dst * HD;
        float p0 = q0 * Kr[o];
        float p1 = q1 * Kr[DH + o];
        float p2 = q2 * Kr[2 * DH + o];
        float p3 = q3 * Kr[3 * DH + o];
        #pragma unroll
        for (int m = 1; m < 32; m <<= 1) {
            p0 += __shfl_xor(p0, m, 64);
            p1 += __shfl_xor(p1, m, 64);
            p2 += __shfl_xor(p2, m, 64);
            p3 += __shfl_xor(p3, m, 64);
        }
        const float s0 = (p0 + ee.x) * 0.17677669529663687f;
        const float s1 = (p1 + ee.y) * 0.17677669529663687f;
        const float s2 = (p2 + ee.z) * 0.17677669529663687f;
        const float s3 = (p3 + ee.w) * 0.17677669529663687f;
        const float mx = fmaxf(fmaxf(s0, s1), fmaxf(s2, s3));
        const float a0 = __expf(s0 - mx), a1 = __expf(s1 - mx);
        const float a2 = __expf(s2 - mx), a3 = __expf(s3 - mx);
        const float inv = 1.f / (a0 + a1 + a2 + a3);
        const float* __restrict__ Pr = P + (size_t)dst * HD;
        float c = a0 * Pr[o] + a1 * Pr[DH + o] + a2 * Pr[2 * DH + o] + a3 * Pr[3 * DH + o];
        acc = fmaf(c, inv, acc);
    }
    red[g][o] = acc;
    __syncthreads();
    if (tid < 32) {
        const float s = red[0][o] + red[1][o] + red[2][o] + red[3][o]
                      + red[4][o] + red[5][o] + red[6][o] + red[7][o];
        out[(size_t)n * OUT_DIM + o] = (d > 0) ? (s / (float)d + bo[o]) : 0.f;
    }
}

extern "C" void kernel_launch(void* const* d_in, const int* in_sizes, int n_in,
                              void* d_out, int out_size, void* d_ws, size_t ws_size,
                              hipStream_t stream)
{
    const float* x   = (const float*)d_in[0];
    const int*   ei  = (const int*)  d_in[1];
    const float* ea  = (const float*)d_in[2];
    const float* Wq  = (const float*)d_in[3];
    const float* bq  = (const float*)d_in[4];
    const float* Wk  = (const float*)d_in[5];
    const float* bk  = (const float*)d_in[6];
    const float* Wv  = (const float*)d_in[7];
    const float* bv  = (const float*)d_in[8];
    const float* We  = (const float*)d_in[9];
    const float* be  = (const float*)d_in[10];
    const float* Wo  = (const float*)d_in[11];
    const float* bo  = (const float*)d_in[12];
    float* out = (float*)d_out;

    // workspace layout (16B-aligned chunks)
    float*  Q    = (float*)d_ws;                        // NN*HD
    float*  K    = Q + (size_t)NN * HD;                 // NN*HD
    float*  P    = K + (size_t)NN * HD;                 // NN*HD
    float4* cee  = (float4*)(P + (size_t)NN * HD);      // NE_
    int*    cdst = (int*)(cee + NE_);                   // NE_
    unsigned short* frag_hi = (unsigned short*)(cdst + NE_);     // 4096
    unsigned short* frag_lo = frag_hi + 8 * 64 * 8;              // 4096
    int* deg = (int*)(frag_lo + 8 * 64 * 8);            // NN
    int* off = deg + NN;                                // NN
    int* cur = off + NN;                                // NN

    hipMemsetAsync(deg, 0, NN * sizeof(int), stream);

    qkvp_kernel<<<NN, 128, 0, stream>>>(x, Wq, bq, Wk, bk, Wv, bv, Wo, Q, K, P);
    wet_kernel<<<1, 512, 0, stream>>>(We, frag_hi, frag_lo);
    hist_kernel<<<(NE_ + 255) / 256, 256, 0, stream>>>(ei, deg);
    scan_kernel<<<1, SCAN_T, 0, stream>>>(deg, off, cur);
    ee_scatter_kernel<<<NE_ / 256, 256, 0, stream>>>(ea, frag_hi, frag_lo, be,
                                                     ei, cur, cdst, cee);
    fused_gather_kernel<<<NN, 256, 0, stream>>>(off, deg, cdst, cee, Q, K, P, bo, out);
}

// Round 5
// 233.316 us; speedup vs baseline: 2.1931x; 1.1269x over previous
//
#include <hip/hip_runtime.h>

#define NN      10000
#define IN_DIM  128
#define E_DIM   32
#define NH      4
#define DH      32
#define HD      128   // NH*DH
#define NE_     640000
#define OUT_DIM 32
#define SCAN_T  1024
#define CHUNK   10    // SCAN_T*CHUNK >= NN
#define NB      16    // nodes per qkvp block (NN % NB == 0)

typedef __attribute__((ext_vector_type(8))) short bf16x8;
typedef __attribute__((ext_vector_type(4))) float f32x4;

static __device__ __forceinline__ unsigned short f32_to_bf16_rne(float f) {
    unsigned u = __float_as_uint(f);
    return (unsigned short)((u + 0x7fffu + ((u >> 16) & 1u)) >> 16);
}
static __device__ __forceinline__ float bf16_bits_to_f32(unsigned short h) {
    return __uint_as_float(((unsigned)h) << 16);
}
static __device__ __forceinline__ float sel4(const float r[4], int at) {
    const float lo = (at & 1) ? r[1] : r[0];
    const float hi = (at & 1) ? r[3] : r[2];
    return (at & 2) ? hi : lo;
}

// ---------------------------------------------------------------------------
// Kernel 1: 16 nodes per block (weight reuse).
//   Phase A (thread = (half, col j)): q,k,v for 8 nodes each, W read once/block.
//   Phase B: PT[n][o*4+h] = sum_d V[n][h*32+d] * Wo[(h*32+d)*32+o]
// ---------------------------------------------------------------------------
__global__ __launch_bounds__(256) void qkvp_kernel(
    const float* __restrict__ x,
    const float* __restrict__ Wq, const float* __restrict__ bq,
    const float* __restrict__ Wk, const float* __restrict__ bk,
    const float* __restrict__ Wv, const float* __restrict__ bv,
    const float* __restrict__ Wo,
    float* __restrict__ Q, float* __restrict__ K, float* __restrict__ PT)
{
    __shared__ float xs[NB][IN_DIM];
    __shared__ float vs[NB][IN_DIM + 4];   // +4 pad: nodes spread across banks
    const int t = threadIdx.x;
    const int base = blockIdx.x * NB;

    #pragma unroll
    for (int r = 0; r < NB * IN_DIM / 256; ++r) {
        const int idx = r * 256 + t;
        const int nn = idx >> 7, col = idx & 127;
        xs[nn][col] = x[(size_t)(base + nn) * IN_DIM + col];
    }
    __syncthreads();

    const int j = t & 127;
    const int half = t >> 7;            // nodes half*8 .. half*8+7
    const float bqj = bq[j], bkj = bk[j], bvj = bv[j];
    float q[8], k[8], v[8];
    #pragma unroll
    for (int m = 0; m < 8; ++m) { q[m] = bqj; k[m] = bkj; v[m] = bvj; }

    #pragma unroll 2
    for (int i = 0; i < IN_DIM; ++i) {
        const float wq = Wq[i * HD + j];
        const float wk = Wk[i * HD + j];
        const float wv = Wv[i * HD + j];
        #pragma unroll
        for (int m = 0; m < 8; ++m) {
            const float xv = xs[half * 8 + m][i];
            q[m] = fmaf(xv, wq, q[m]);
            k[m] = fmaf(xv, wk, k[m]);
            v[m] = fmaf(xv, wv, v[m]);
        }
    }
    #pragma unroll
    for (int m = 0; m < 8; ++m) {
        const int n = half * 8 + m;
        Q[(size_t)(base + n) * HD + j] = q[m];
        K[(size_t)(base + n) * HD + j] = k[m];
        vs[n][j] = v[m];
    }
    __syncthreads();

    // Phase B: 16 threads per node; thread u handles flat = u*8+w, w=0..7
    // flat = o*4 + h  ->  h = w & 3 (uniform over u), o = u*2 + (w>>2)
    const int nn2 = t >> 4, u = t & 15;
    float pv[8];
    #pragma unroll
    for (int w = 0; w < 8; ++w) {
        const int h = w & 3, o = u * 2 + (w >> 2);
        float p = 0.f;
        #pragma unroll 4
        for (int d2 = 0; d2 < DH; ++d2)
            p = fmaf(vs[nn2][h * DH + d2], Wo[(h * DH + d2) * OUT_DIM + o], p);
        pv[w] = p;
    }
    float* dst = PT + (size_t)(base + nn2) * HD + u * 8;
    *reinterpret_cast<float4*>(dst)     = make_float4(pv[0], pv[1], pv[2], pv[3]);
    *reinterpret_cast<float4*>(dst + 4) = make_float4(pv[4], pv[5], pv[6], pv[7]);
}

// ---------------------------------------------------------------------------
// Kernel 1b: pre-swizzled bf16 hi/lo MFMA A-fragments of We.
//   A-tile t (16 d-cols), lane l, elem j:  We[k = (l>>4)*8+j][d = t*16 + (l&15)]
// ---------------------------------------------------------------------------
__global__ __launch_bounds__(512) void wet_kernel(
    const float* __restrict__ We,
    unsigned short* __restrict__ frag_hi, unsigned short* __restrict__ frag_lo)
{
    const int tid = threadIdx.x;        // tid = t*64 + l
    const int l = tid & 63, t = tid >> 6;
    #pragma unroll
    for (int j = 0; j < 8; ++j) {
        const int k = (l >> 4) * 8 + j;
        const int d = t * 16 + (l & 15);
        const float w = We[k * HD + d];
        const unsigned short hi = f32_to_bf16_rne(w);
        const unsigned short lo = f32_to_bf16_rne(w - bf16_bits_to_f32(hi));
        frag_hi[tid * 8 + j] = hi;
        frag_lo[tid * 8 + j] = lo;
    }
}

// ---------------------------------------------------------------------------
// Kernel 2: degree histogram over src
// ---------------------------------------------------------------------------
__global__ __launch_bounds__(256) void hist_kernel(
    const int* __restrict__ ei, int* __restrict__ deg)
{
    const int e = blockIdx.x * blockDim.x + threadIdx.x;
    if (e >= NE_) return;
    atomicAdd(&deg[ei[e]], 1);
}

// ---------------------------------------------------------------------------
// Kernel 3: exclusive scan of deg -> off, cur (shfl-based, 2 barriers)
// ---------------------------------------------------------------------------
__global__ __launch_bounds__(SCAN_T) void scan_kernel(
    const int* __restrict__ deg, int* __restrict__ off, int* __restrict__ cur)
{
    __shared__ int wsum[16];
    const int t = threadIdx.x;
    const int lane = t & 63, w = t >> 6;
    const int base = t * CHUNK;
    int v[CHUNK];
    int sum = 0;
    #pragma unroll
    for (int i = 0; i < CHUNK; ++i) {
        const int idx = base + i;
        v[i] = (idx < NN) ? deg[idx] : 0;
        sum += v[i];
    }
    int incl = sum;
    #pragma unroll
    for (int dlt = 1; dlt < 64; dlt <<= 1) {
        const int nb = __shfl_up(incl, dlt, 64);
        if (lane >= dlt) incl += nb;
    }
    if (lane == 63) wsum[w] = incl;
    __syncthreads();
    if (w == 0) {
        const int val = (lane < 16) ? wsum[lane] : 0;
        int wi = val;
        #pragma unroll
        for (int dlt = 1; dlt < 16; dlt <<= 1) {
            const int nb = __shfl_up(wi, dlt, 64);
            if (lane >= dlt) wi += nb;
        }
        if (lane < 16) wsum[lane] = wi - val;   // exclusive wave prefix
    }
    __syncthreads();
    int run = wsum[w] + (incl - sum);
    #pragma unroll
    for (int i = 0; i < CHUNK; ++i) {
        const int idx = base + i;
        if (idx < NN) { off[idx] = run; cur[idx] = run; run += v[i]; }
    }
}

// ---------------------------------------------------------------------------
// Kernel 4: ee via split-bf16 MFMA + full-wave CSR slot scatter.
//   lane l owns edge base+l; payload = (dst, ee0-ee3, ee1-ee3, ee2-ee3)
//   (softmax is shift-invariant over heads, so ee3 folds to 0)
// ---------------------------------------------------------------------------
__global__ __launch_bounds__(256) void ee_scatter_kernel(
    const float* __restrict__ ea,
    const unsigned short* __restrict__ frag_hi,
    const unsigned short* __restrict__ frag_lo,
    const float* __restrict__ be,
    const int* __restrict__ ei,
    int* __restrict__ cur, float4* __restrict__ pay)
{
    const int lane = threadIdx.x & 63;
    const int wave = threadIdx.x >> 6;
    const int base = blockIdx.x * 256 + wave * 64;   // 64 edges per wave

    // prefetch this lane's edge endpoints (coalesced)
    const int src = ei[base + lane];
    const int dstn = ei[NE_ + base + lane];

    // load + convert ea B-fragments for 4 tiles of 16 edges
    bf16x8 eahi[4], ealo[4];
    const int erow = lane & 15;
    const int kc = lane >> 4;          // k-chunk 0..3
    #pragma unroll
    for (int at = 0; at < 4; ++at) {
        const float* ar = ea + (size_t)(base + at * 16 + erow) * E_DIM + kc * 8;
        const float4 a0 = *reinterpret_cast<const float4*>(ar);
        const float4 a1 = *reinterpret_cast<const float4*>(ar + 4);
        float av[8] = {a0.x, a0.y, a0.z, a0.w, a1.x, a1.y, a1.z, a1.w};
        #pragma unroll
        for (int j = 0; j < 8; ++j) {
            const unsigned short hi = f32_to_bf16_rne(av[j]);
            const unsigned short lo = f32_to_bf16_rne(av[j] - bf16_bits_to_f32(hi));
            eahi[at][j] = (short)hi;
            ealo[at][j] = (short)lo;
        }
    }

    float part[4][NH] = {};   // [at][h] partial ef^2 over this lane's d rows

    #pragma unroll
    for (int t = 0; t < 8; ++t) {      // 8 d-tiles of 16
        const bf16x8 whi = *reinterpret_cast<const bf16x8*>(frag_hi + ((t * 64 + lane) << 3));
        const bf16x8 wlo = *reinterpret_cast<const bf16x8*>(frag_lo + ((t * 64 + lane) << 3));
        const float4 be4 = *reinterpret_cast<const float4*>(be + t * 16 + ((lane >> 4) << 2));
        #pragma unroll
        for (int at = 0; at < 4; ++at) {
            f32x4 acc = {0.f, 0.f, 0.f, 0.f};
            acc = __builtin_amdgcn_mfma_f32_16x16x32_bf16(whi, eahi[at], acc, 0, 0, 0);
            acc = __builtin_amdgcn_mfma_f32_16x16x32_bf16(whi, ealo[at], acc, 0, 0, 0);
            acc = __builtin_amdgcn_mfma_f32_16x16x32_bf16(wlo, eahi[at], acc, 0, 0, 0);
            const float e0 = acc[0] + be4.x, e1 = acc[1] + be4.y;
            const float e2 = acc[2] + be4.z, e3 = acc[3] + be4.w;
            part[at][t >> 1] += e0 * e0 + e1 * e1 + e2 * e2 + e3 * e3;
        }
    }

    float red0[4], red1[4], red2[4], red3[4];
    #pragma unroll
    for (int at = 0; at < 4; ++at) {
        float v0 = part[at][0]; v0 += __shfl_xor(v0, 16, 64); v0 += __shfl_xor(v0, 32, 64);
        float v1 = part[at][1]; v1 += __shfl_xor(v1, 16, 64); v1 += __shfl_xor(v1, 32, 64);
        float v2 = part[at][2]; v2 += __shfl_xor(v2, 16, 64); v2 += __shfl_xor(v2, 32, 64);
        float v3 = part[at][3]; v3 += __shfl_xor(v3, 16, 64); v3 += __shfl_xor(v3, 32, 64);
        red0[at] = v0; red1[at] = v1; red2[at] = v2; red3[at] = v3;
    }

    // lane l owns edge base+l  (tile at = l>>4, row r = l&15)
    const int at = lane >> 4;
    const float w0 = sel4(red0, at), w1 = sel4(red1, at);
    const float w2 = sel4(red2, at), w3 = sel4(red3, at);

    const int pos = atomicAdd(&cur[src], 1);
    pay[pos] = make_float4(__int_as_float(dstn), w0 - w3, w1 - w3, w2 - w3);
}

// ---------------------------------------------------------------------------
// Kernel 5: fused score+softmax+aggregate, CSR order.
//   block = node n, 8 groups of 32 lanes; group = one edge/iter.
//   lane o: h = o>>3; qk partial on dims o*4..o*4+3; 6-shuffle reduce+bcast.
// ---------------------------------------------------------------------------
__global__ __launch_bounds__(256) void fused_gather_kernel(
    const int* __restrict__ off, const int* __restrict__ deg,
    const float4* __restrict__ pay,
    const float* __restrict__ Q, const float* __restrict__ K,
    const float* __restrict__ PT, const float* __restrict__ bo,
    float* __restrict__ out)
{
    __shared__ float red[8][OUT_DIM];
    const int n = blockIdx.x;
    const int d = deg[n];
    const int start = off[n];
    const int tid = threadIdx.x;
    const int g = tid >> 5, o = tid & 31;
    const int h = o >> 3;
    const float scale = 0.17677669529663687f;  // 1/sqrt(32)

    const float4 q4 = *reinterpret_cast<const float4*>(Q + (size_t)n * HD + o * 4);

    float acc = 0.f;
    float4 pc = make_float4(0.f, 0.f, 0.f, 0.f);
    if (g < d) pc = pay[start + g];

    for (int i = g; i < d; i += 8) {
        float4 pn = make_float4(0.f, 0.f, 0.f, 0.f);
        if (i + 8 < d) pn = pay[start + i + 8];   // prefetch next iter

        const int dst = __float_as_int(pc.x);
        const float4 k4 = *reinterpret_cast<const float4*>(K  + (size_t)dst * HD + o * 4);
        const float4 p4 = *reinterpret_cast<const float4*>(PT + (size_t)dst * HD + o * 4);

        float p = fmaf(q4.x, k4.x, fmaf(q4.y, k4.y, fmaf(q4.z, k4.z, q4.w * k4.w)));
        p += __shfl_xor(p, 1, 64);
        p += __shfl_xor(p, 2, 64);
        p += __shfl_xor(p, 4, 64);
        // broadcast all 4 head sums to every lane
        const float b  = __shfl_xor(p, 8, 64);
        const float e0 = (h & 1) ? b : p;
        const float e1 = (h & 1) ? p : b;
        const float o0 = __shfl_xor(e0, 16, 64);
        const float o1 = __shfl_xor(e1, 16, 64);
        const float qk0 = (h & 2) ? o0 : e0;
        const float qk1 = (h & 2) ? o1 : e1;
        const float qk2 = (h & 2) ? e0 : o0;
        const float qk3 = (h & 2) ? e1 : o1;

        const float s0 = (qk0 + pc.y) * scale;
        const float s1 = (qk1 + pc.z) * scale;
        const float s2 = (qk2 + pc.w) * scale;
        const float s3 = qk3 * scale;
        const float mx = fmaxf(fmaxf(s0, s1), fmaxf(s2, s3));
        const float a0 = __expf(s0 - mx), a1 = __expf(s1 - mx);
        const float a2 = __expf(s2 - mx), a3 = __expf(s3 - mx);
        const float inv = 1.f / (a0 + a1 + a2 + a3);
        const float c = fmaf(a0, p4.x, fmaf(a1, p4.y, fmaf(a2, p4.z, a3 * p4.w)));
        acc = fmaf(c, inv, acc);
        pc = pn;
    }
    red[g][o] = acc;
    __syncthreads();
    if (tid < 32) {
        const float s = red[0][o] + red[1][o] + red[2][o] + red[3][o]
                      + red[4][o] + red[5][o] + red[6][o] + red[7][o];
        out[(size_t)n * OUT_DIM + o] = (d > 0) ? (s / (float)d + bo[o]) : 0.f;
    }
}

extern "C" void kernel_launch(void* const* d_in, const int* in_sizes, int n_in,
                              void* d_out, int out_size, void* d_ws, size_t ws_size,
                              hipStream_t stream)
{
    const float* x   = (const float*)d_in[0];
    const int*   ei  = (const int*)  d_in[1];
    const float* ea  = (const float*)d_in[2];
    const float* Wq  = (const float*)d_in[3];
    const float* bq  = (const float*)d_in[4];
    const float* Wk  = (const float*)d_in[5];
    const float* bk  = (const float*)d_in[6];
    const float* Wv  = (const float*)d_in[7];
    const float* bv  = (const float*)d_in[8];
    const float* We  = (const float*)d_in[9];
    const float* be  = (const float*)d_in[10];
    const float* Wo  = (const float*)d_in[11];
    const float* bo  = (const float*)d_in[12];
    float* out = (float*)d_out;

    // workspace layout
    float*  Q   = (float*)d_ws;                         // NN*HD
    float*  K   = Q + (size_t)NN * HD;                  // NN*HD
    float*  PT  = K + (size_t)NN * HD;                  // NN*HD
    float4* pay = (float4*)(PT + (size_t)NN * HD);      // NE_
    unsigned short* frag_hi = (unsigned short*)(pay + NE_);     // 4096
    unsigned short* frag_lo = frag_hi + 8 * 64 * 8;             // 4096
    int* deg = (int*)(frag_lo + 8 * 64 * 8);            // NN
    int* off = deg + NN;                                // NN
    int* cur = off + NN;                                // NN

    hipMemsetAsync(deg, 0, NN * sizeof(int), stream);

    qkvp_kernel<<<NN / NB, 256, 0, stream>>>(x, Wq, bq, Wk, bk, Wv, bv, Wo, Q, K, PT);
    wet_kernel<<<1, 512, 0, stream>>>(We, frag_hi, frag_lo);
    hist_kernel<<<(NE_ + 255) / 256, 256, 0, stream>>>(ei, deg);
    scan_kernel<<<1, SCAN_T, 0, stream>>>(deg, off, cur);
    ee_scatter_kernel<<<NE_ / 256, 256, 0, stream>>>(ea, frag_hi, frag_lo, be,
                                                     ei, cur, pay);
    fused_gather_kernel<<<NN, 256, 0, stream>>>(off, deg, pay, Q, K, PT, bo, out);
}

// Round 6
// 224.134 us; speedup vs baseline: 2.2830x; 1.0410x over previous
//
#include <hip/hip_runtime.h>

#define NN      10000
#define IN_DIM  128
#define E_DIM   32
#define NH      4
#define DH      32
#define HD      128   // NH*DH
#define NE_     640000
#define OUT_DIM 32
#define SCAN_T  1024
#define CHUNK   10    // SCAN_T*CHUNK >= NN
#define NB      16    // nodes per qkvp block (NN % NB == 0)

typedef __attribute__((ext_vector_type(8))) short bf16x8;
typedef __attribute__((ext_vector_type(4))) float f32x4;

static __device__ __forceinline__ unsigned short f32_to_bf16_rne(float f) {
    unsigned u = __float_as_uint(f);
    return (unsigned short)((u + 0x7fffu + ((u >> 16) & 1u)) >> 16);
}
static __device__ __forceinline__ float bf16_bits_to_f32(unsigned short h) {
    return __uint_as_float(((unsigned)h) << 16);
}
static __device__ __forceinline__ float sel4(const float r[4], int at) {
    const float lo = (at & 1) ? r[1] : r[0];
    const float hi = (at & 1) ? r[3] : r[2];
    return (at & 2) ? hi : lo;
}

// ---------------------------------------------------------------------------
// Kernel 1: 16 nodes per block (weight reuse).
//   Phase A (thread = (half, col j)): q,k,v for 8 nodes each, W read once/block.
//   Phase B: PTb[n][o*4+h] = bf16( sum_d V[n][h*32+d] * Wo[(h*32+d)*32+o] )
// ---------------------------------------------------------------------------
__global__ __launch_bounds__(256) void qkvp_kernel(
    const float* __restrict__ x,
    const float* __restrict__ Wq, const float* __restrict__ bq,
    const float* __restrict__ Wk, const float* __restrict__ bk,
    const float* __restrict__ Wv, const float* __restrict__ bv,
    const float* __restrict__ Wo,
    float* __restrict__ Q, float* __restrict__ K,
    unsigned short* __restrict__ PTb)
{
    __shared__ float xs[NB][IN_DIM];
    __shared__ float vs[NB][IN_DIM + 4];   // +4 pad: nodes spread across banks
    const int t = threadIdx.x;
    const int base = blockIdx.x * NB;

    #pragma unroll
    for (int r = 0; r < NB * IN_DIM / 256; ++r) {
        const int idx = r * 256 + t;
        const int nn = idx >> 7, col = idx & 127;
        xs[nn][col] = x[(size_t)(base + nn) * IN_DIM + col];
    }
    __syncthreads();

    const int j = t & 127;
    const int half = t >> 7;            // nodes half*8 .. half*8+7
    const float bqj = bq[j], bkj = bk[j], bvj = bv[j];
    float q[8], k[8], v[8];
    #pragma unroll
    for (int m = 0; m < 8; ++m) { q[m] = bqj; k[m] = bkj; v[m] = bvj; }

    #pragma unroll 2
    for (int i = 0; i < IN_DIM; ++i) {
        const float wq = Wq[i * HD + j];
        const float wk = Wk[i * HD + j];
        const float wv = Wv[i * HD + j];
        #pragma unroll
        for (int m = 0; m < 8; ++m) {
            const float xv = xs[half * 8 + m][i];
            q[m] = fmaf(xv, wq, q[m]);
            k[m] = fmaf(xv, wk, k[m]);
            v[m] = fmaf(xv, wv, v[m]);
        }
    }
    #pragma unroll
    for (int m = 0; m < 8; ++m) {
        const int n = half * 8 + m;
        Q[(size_t)(base + n) * HD + j] = q[m];
        K[(size_t)(base + n) * HD + j] = k[m];
        vs[n][j] = v[m];
    }
    __syncthreads();

    // Phase B: 16 threads per node; thread u handles flat = u*8+w, w=0..7
    // flat = o*4 + h  ->  h = w & 3 (uniform over u), o = u*2 + (w>>2)
    const int nn2 = t >> 4, u = t & 15;
    unsigned short us[8];
    #pragma unroll
    for (int w = 0; w < 8; ++w) {
        const int h = w & 3, o = u * 2 + (w >> 2);
        float p = 0.f;
        #pragma unroll 4
        for (int d2 = 0; d2 < DH; ++d2)
            p = fmaf(vs[nn2][h * DH + d2], Wo[(h * DH + d2) * OUT_DIM + o], p);
        us[w] = f32_to_bf16_rne(p);
    }
    *reinterpret_cast<uint4*>(PTb + (size_t)(base + nn2) * HD + u * 8) =
        *reinterpret_cast<const uint4*>(us);
}

// ---------------------------------------------------------------------------
// Kernel 1b: pre-swizzled bf16 hi/lo MFMA A-fragments of We.
//   A-tile t (16 d-cols), lane l, elem j:  We[k = (l>>4)*8+j][d = t*16 + (l&15)]
// ---------------------------------------------------------------------------
__global__ __launch_bounds__(512) void wet_kernel(
    const float* __restrict__ We,
    unsigned short* __restrict__ frag_hi, unsigned short* __restrict__ frag_lo)
{
    const int tid = threadIdx.x;        // tid = t*64 + l
    const int l = tid & 63, t = tid >> 6;
    #pragma unroll
    for (int j = 0; j < 8; ++j) {
        const int k = (l >> 4) * 8 + j;
        const int d = t * 16 + (l & 15);
        const float w = We[k * HD + d];
        const unsigned short hi = f32_to_bf16_rne(w);
        const unsigned short lo = f32_to_bf16_rne(w - bf16_bits_to_f32(hi));
        frag_hi[tid * 8 + j] = hi;
        frag_lo[tid * 8 + j] = lo;
    }
}

// ---------------------------------------------------------------------------
// Kernel 2: degree histogram over src + per-edge rank (coalesced write).
//   rank[e] = #prior arrivals for this src (atomic order; permutes fp-sum
//   order within a node segment only).
// ---------------------------------------------------------------------------
__global__ __launch_bounds__(256) void hist_rank_kernel(
    const int* __restrict__ ei, int* __restrict__ deg, int* __restrict__ rank)
{
    const int e = blockIdx.x * blockDim.x + threadIdx.x;
    if (e >= NE_) return;
    rank[e] = atomicAdd(&deg[ei[e]], 1);
}

// ---------------------------------------------------------------------------
// Kernel 3: exclusive scan of deg -> off (shfl-based, 2 barriers)
// ---------------------------------------------------------------------------
__global__ __launch_bounds__(SCAN_T) void scan_kernel(
    const int* __restrict__ deg, int* __restrict__ off)
{
    __shared__ int wsum[16];
    const int t = threadIdx.x;
    const int lane = t & 63, w = t >> 6;
    const int base = t * CHUNK;
    int v[CHUNK];
    int sum = 0;
    #pragma unroll
    for (int i = 0; i < CHUNK; ++i) {
        const int idx = base + i;
        v[i] = (idx < NN) ? deg[idx] : 0;
        sum += v[i];
    }
    int incl = sum;
    #pragma unroll
    for (int dlt = 1; dlt < 64; dlt <<= 1) {
        const int nb = __shfl_up(incl, dlt, 64);
        if (lane >= dlt) incl += nb;
    }
    if (lane == 63) wsum[w] = incl;
    __syncthreads();
    if (w == 0) {
        const int val = (lane < 16) ? wsum[lane] : 0;
        int wi = val;
        #pragma unroll
        for (int dlt = 1; dlt < 16; dlt <<= 1) {
            const int nb = __shfl_up(wi, dlt, 64);
            if (lane >= dlt) wi += nb;
        }
        if (lane < 16) wsum[lane] = wi - val;   // exclusive wave prefix
    }
    __syncthreads();
    int run = wsum[w] + (incl - sum);
    #pragma unroll
    for (int i = 0; i < CHUNK; ++i) {
        const int idx = base + i;
        if (idx < NN) { off[idx] = run; run += v[i]; }
    }
}

// ---------------------------------------------------------------------------
// Kernel 4: ee via split-bf16 MFMA; plain (non-atomic) 16B scatter to CSR slot
//   pos = off[src] + rank[e].  payload = (dst, ee0-ee3, ee1-ee3, ee2-ee3).
// ---------------------------------------------------------------------------
__global__ __launch_bounds__(256) void ee_scatter_kernel(
    const float* __restrict__ ea,
    const unsigned short* __restrict__ frag_hi,
    const unsigned short* __restrict__ frag_lo,
    const float* __restrict__ be,
    const int* __restrict__ ei,
    const int* __restrict__ off, const int* __restrict__ rank,
    float4* __restrict__ pay)
{
    const int lane = threadIdx.x & 63;
    const int wave = threadIdx.x >> 6;
    const int base = blockIdx.x * 256 + wave * 64;   // 64 edges per wave

    // this lane's edge metadata (all coalesced; off[] is a 40KB hot gather)
    const int src  = ei[base + lane];
    const int dstn = ei[NE_ + base + lane];
    const int pos  = off[src] + rank[base + lane];

    // load + convert ea B-fragments for 4 tiles of 16 edges
    bf16x8 eahi[4], ealo[4];
    const int erow = lane & 15;
    const int kc = lane >> 4;          // k-chunk 0..3
    #pragma unroll
    for (int at = 0; at < 4; ++at) {
        const float* ar = ea + (size_t)(base + at * 16 + erow) * E_DIM + kc * 8;
        const float4 a0 = *reinterpret_cast<const float4*>(ar);
        const float4 a1 = *reinterpret_cast<const float4*>(ar + 4);
        float av[8] = {a0.x, a0.y, a0.z, a0.w, a1.x, a1.y, a1.z, a1.w};
        #pragma unroll
        for (int j = 0; j < 8; ++j) {
            const unsigned short hi = f32_to_bf16_rne(av[j]);
            const unsigned short lo = f32_to_bf16_rne(av[j] - bf16_bits_to_f32(hi));
            eahi[at][j] = (short)hi;
            ealo[at][j] = (short)lo;
        }
    }

    float part[4][NH] = {};   // [at][h] partial ef^2 over this lane's d rows

    #pragma unroll
    for (int t = 0; t < 8; ++t) {      // 8 d-tiles of 16
        const bf16x8 whi = *reinterpret_cast<const bf16x8*>(frag_hi + ((t * 64 + lane) << 3));
        const bf16x8 wlo = *reinterpret_cast<const bf16x8*>(frag_lo + ((t * 64 + lane) << 3));
        const float4 be4 = *reinterpret_cast<const float4*>(be + t * 16 + ((lane >> 4) << 2));
        #pragma unroll
        for (int at = 0; at < 4; ++at) {
            f32x4 acc = {0.f, 0.f, 0.f, 0.f};
            acc = __builtin_amdgcn_mfma_f32_16x16x32_bf16(whi, eahi[at], acc, 0, 0, 0);
            acc = __builtin_amdgcn_mfma_f32_16x16x32_bf16(whi, ealo[at], acc, 0, 0, 0);
            acc = __builtin_amdgcn_mfma_f32_16x16x32_bf16(wlo, eahi[at], acc, 0, 0, 0);
            const float e0 = acc[0] + be4.x, e1 = acc[1] + be4.y;
            const float e2 = acc[2] + be4.z, e3 = acc[3] + be4.w;
            part[at][t >> 1] += e0 * e0 + e1 * e1 + e2 * e2 + e3 * e3;
        }
    }

    float red0[4], red1[4], red2[4], red3[4];
    #pragma unroll
    for (int at = 0; at < 4; ++at) {
        float v0 = part[at][0]; v0 += __shfl_xor(v0, 16, 64); v0 += __shfl_xor(v0, 32, 64);
        float v1 = part[at][1]; v1 += __shfl_xor(v1, 16, 64); v1 += __shfl_xor(v1, 32, 64);
        float v2 = part[at][2]; v2 += __shfl_xor(v2, 16, 64); v2 += __shfl_xor(v2, 32, 64);
        float v3 = part[at][3]; v3 += __shfl_xor(v3, 16, 64); v3 += __shfl_xor(v3, 32, 64);
        red0[at] = v0; red1[at] = v1; red2[at] = v2; red3[at] = v3;
    }

    // lane l owns edge base+l  (tile at = l>>4, row r = l&15)
    const int at = lane >> 4;
    const float w0 = sel4(red0, at), w1 = sel4(red1, at);
    const float w2 = sel4(red2, at), w3 = sel4(red3, at);

    pay[pos] = make_float4(__int_as_float(dstn), w0 - w3, w1 - w3, w2 - w3);
}

// ---------------------------------------------------------------------------
// Kernel 5: fused score+softmax+aggregate, CSR order.
//   block = node n, 8 groups of 32 lanes; group = one edge/iter.
//   lane o: h = o>>3; qk partial on dims o*4..o*4+3; 6-shuffle reduce+bcast.
// ---------------------------------------------------------------------------
__global__ __launch_bounds__(256) void fused_gather_kernel(
    const int* __restrict__ off, const int* __restrict__ deg,
    const float4* __restrict__ pay,
    const float* __restrict__ Q, const float* __restrict__ K,
    const unsigned short* __restrict__ PTb, const float* __restrict__ bo,
    float* __restrict__ out)
{
    __shared__ float red[8][OUT_DIM];
    const int n = blockIdx.x;
    const int d = deg[n];
    const int start = off[n];
    const int tid = threadIdx.x;
    const int g = tid >> 5, o = tid & 31;
    const int h = o >> 3;
    const float scale = 0.17677669529663687f;  // 1/sqrt(32)

    const float4 q4 = *reinterpret_cast<const float4*>(Q + (size_t)n * HD + o * 4);

    float acc = 0.f;
    float4 pc = make_float4(0.f, 0.f, 0.f, 0.f);
    if (g < d) pc = pay[start + g];

    for (int i = g; i < d; i += 8) {
        float4 pn = make_float4(0.f, 0.f, 0.f, 0.f);
        if (i + 8 < d) pn = pay[start + i + 8];   // prefetch next iter

        const int dst = __float_as_int(pc.x);
        const float4 k4 = *reinterpret_cast<const float4*>(K + (size_t)dst * HD + o * 4);
        const ushort4 pb = *reinterpret_cast<const ushort4*>(PTb + (size_t)dst * HD + o * 4);

        float p = fmaf(q4.x, k4.x, fmaf(q4.y, k4.y, fmaf(q4.z, k4.z, q4.w * k4.w)));
        p += __shfl_xor(p, 1, 64);
        p += __shfl_xor(p, 2, 64);
        p += __shfl_xor(p, 4, 64);
        // broadcast all 4 head sums to every lane
        const float b  = __shfl_xor(p, 8, 64);
        const float e0 = (h & 1) ? b : p;
        const float e1 = (h & 1) ? p : b;
        const float o0 = __shfl_xor(e0, 16, 64);
        const float o1 = __shfl_xor(e1, 16, 64);
        const float qk0 = (h & 2) ? o0 : e0;
        const float qk1 = (h & 2) ? o1 : e1;
        const float qk2 = (h & 2) ? e0 : o0;
        const float qk3 = (h & 2) ? e1 : o1;

        const float s0 = (qk0 + pc.y) * scale;
        const float s1 = (qk1 + pc.z) * scale;
        const float s2 = (qk2 + pc.w) * scale;
        const float s3 = qk3 * scale;
        const float mx = fmaxf(fmaxf(s0, s1), fmaxf(s2, s3));
        const float a0 = __expf(s0 - mx), a1 = __expf(s1 - mx);
        const float a2 = __expf(s2 - mx), a3 = __expf(s3 - mx);
        const float inv = 1.f / (a0 + a1 + a2 + a3);
        const float c = fmaf(a0, bf16_bits_to_f32(pb.x),
                        fmaf(a1, bf16_bits_to_f32(pb.y),
                        fmaf(a2, bf16_bits_to_f32(pb.z),
                             a3 * bf16_bits_to_f32(pb.w))));
        acc = fmaf(c, inv, acc);
        pc = pn;
    }
    red[g][o] = acc;
    __syncthreads();
    if (tid < 32) {
        const float s = red[0][o] + red[1][o] + red[2][o] + red[3][o]
                      + red[4][o] + red[5][o] + red[6][o] + red[7][o];
        out[(size_t)n * OUT_DIM + o] = (d > 0) ? (s / (float)d + bo[o]) : 0.f;
    }
}

extern "C" void kernel_launch(void* const* d_in, const int* in_sizes, int n_in,
                              void* d_out, int out_size, void* d_ws, size_t ws_size,
                              hipStream_t stream)
{
    const float* x   = (const float*)d_in[0];
    const int*   ei  = (const int*)  d_in[1];
    const float* ea  = (const float*)d_in[2];
    const float* Wq  = (const float*)d_in[3];
    const float* bq  = (const float*)d_in[4];
    const float* Wk  = (const float*)d_in[5];
    const float* bk  = (const float*)d_in[6];
    const float* Wv  = (const float*)d_in[7];
    const float* bv  = (const float*)d_in[8];
    const float* We  = (const float*)d_in[9];
    const float* be  = (const float*)d_in[10];
    const float* Wo  = (const float*)d_in[11];
    const float* bo  = (const float*)d_in[12];
    float* out = (float*)d_out;

    // workspace layout (16B-aligned chunks)
    float*  Q   = (float*)d_ws;                         // NN*HD f32
    float*  K   = Q + (size_t)NN * HD;                  // NN*HD f32
    float4* pay = (float4*)(K + (size_t)NN * HD);       // NE_ float4
    unsigned short* PTb = (unsigned short*)(pay + NE_); // NN*HD bf16
    unsigned short* frag_hi = PTb + (size_t)NN * HD;    // 4096
    unsigned short* frag_lo = frag_hi + 8 * 64 * 8;     // 4096
    int* rank = (int*)(frag_lo + 8 * 64 * 8);           // NE_
    int* deg  = rank + NE_;                             // NN
    int* off  = deg + NN;                               // NN

    hipMemsetAsync(deg, 0, NN * sizeof(int), stream);

    qkvp_kernel<<<NN / NB, 256, 0, stream>>>(x, Wq, bq, Wk, bk, Wv, bv, Wo, Q, K, PTb);
    wet_kernel<<<1, 512, 0, stream>>>(We, frag_hi, frag_lo);
    hist_rank_kernel<<<(NE_ + 255) / 256, 256, 0, stream>>>(ei, deg, rank);
    scan_kernel<<<1, SCAN_T, 0, stream>>>(deg, off);
    ee_scatter_kernel<<<NE_ / 256, 256, 0, stream>>>(ea, frag_hi, frag_lo, be,
                                                     ei, off, rank, pay);
    fused_gather_kernel<<<NN, 256, 0, stream>>>(off, deg, pay, Q, K, PTb, bo, out);
}

// Round 7
// 189.960 us; speedup vs baseline: 2.6937x; 1.1799x over previous
//
#include <hip/hip_runtime.h>

#define NN      10000
#define IN_DIM  128
#define E_DIM   32
#define NH      4
#define DH      32
#define HD      128   // NH*DH
#define NE_     640000
#define OUT_DIM 32
#define SCAN_T  1024
#define CHUNK   10    // SCAN_T*CHUNK >= NN
#define NB      16    // nodes per qkvp block (NN % NB == 0)

typedef __attribute__((ext_vector_type(8))) short bf16x8;
typedef __attribute__((ext_vector_type(4))) float f32x4;

static __device__ __forceinline__ unsigned short f32_to_bf16_rne(float f) {
    unsigned u = __float_as_uint(f);
    return (unsigned short)((u + 0x7fffu + ((u >> 16) & 1u)) >> 16);
}
static __device__ __forceinline__ float bf16_bits_to_f32(unsigned short h) {
    return __uint_as_float(((unsigned)h) << 16);
}

// ---------------------------------------------------------------------------
// Kernel 1: 16 nodes per block (weight reuse).
//   Phase A (thread = (half, col j)): q,k,v for 8 nodes each, W read once/block.
//   K is stored as bf16 (Kb). Phase B: PTb[n][o*4+h] = bf16(V[n,h,:]@Wo_h[:,o])
// ---------------------------------------------------------------------------
__global__ __launch_bounds__(256) void qkvp_kernel(
    const float* __restrict__ x,
    const float* __restrict__ Wq, const float* __restrict__ bq,
    const float* __restrict__ Wk, const float* __restrict__ bk,
    const float* __restrict__ Wv, const float* __restrict__ bv,
    const float* __restrict__ Wo,
    float* __restrict__ Q, unsigned short* __restrict__ Kb,
    unsigned short* __restrict__ PTb)
{
    __shared__ float xs[NB][IN_DIM];
    __shared__ float vs[NB][IN_DIM + 4];   // +4 pad: nodes spread across banks
    const int t = threadIdx.x;
    const int base = blockIdx.x * NB;

    #pragma unroll
    for (int r = 0; r < NB * IN_DIM / 256; ++r) {
        const int idx = r * 256 + t;
        const int nn = idx >> 7, col = idx & 127;
        xs[nn][col] = x[(size_t)(base + nn) * IN_DIM + col];
    }
    __syncthreads();

    const int j = t & 127;
    const int half = t >> 7;            // nodes half*8 .. half*8+7
    const float bqj = bq[j], bkj = bk[j], bvj = bv[j];
    float q[8], k[8], v[8];
    #pragma unroll
    for (int m = 0; m < 8; ++m) { q[m] = bqj; k[m] = bkj; v[m] = bvj; }

    #pragma unroll 2
    for (int i = 0; i < IN_DIM; ++i) {
        const float wq = Wq[i * HD + j];
        const float wk = Wk[i * HD + j];
        const float wv = Wv[i * HD + j];
        #pragma unroll
        for (int m = 0; m < 8; ++m) {
            const float xv = xs[half * 8 + m][i];
            q[m] = fmaf(xv, wq, q[m]);
            k[m] = fmaf(xv, wk, k[m]);
            v[m] = fmaf(xv, wv, v[m]);
        }
    }
    #pragma unroll
    for (int m = 0; m < 8; ++m) {
        const int n = half * 8 + m;
        Q[(size_t)(base + n) * HD + j] = q[m];
        Kb[(size_t)(base + n) * HD + j] = f32_to_bf16_rne(k[m]);
        vs[n][j] = v[m];
    }
    __syncthreads();

    // Phase B: 16 threads per node; thread u handles flat = u*8+w, w=0..7
    // flat = o*4 + h  ->  h = w & 3 (uniform over u), o = u*2 + (w>>2)
    const int nn2 = t >> 4, u = t & 15;
    unsigned short us[8];
    #pragma unroll
    for (int w = 0; w < 8; ++w) {
        const int h = w & 3, o = u * 2 + (w >> 2);
        float p = 0.f;
        #pragma unroll 4
        for (int d2 = 0; d2 < DH; ++d2)
            p = fmaf(vs[nn2][h * DH + d2], Wo[(h * DH + d2) * OUT_DIM + o], p);
        us[w] = f32_to_bf16_rne(p);
    }
    *reinterpret_cast<uint4*>(PTb + (size_t)(base + nn2) * HD + u * 8) =
        *reinterpret_cast<const uint4*>(us);
}

// ---------------------------------------------------------------------------
// Kernel 1b: pre-swizzled bf16 hi/lo MFMA A-fragments of We.
//   A-tile t (16 d-cols), lane l, elem j:  We[k = (l>>4)*8+j][d = t*16 + (l&15)]
// ---------------------------------------------------------------------------
__global__ __launch_bounds__(512) void wet_kernel(
    const float* __restrict__ We,
    unsigned short* __restrict__ frag_hi, unsigned short* __restrict__ frag_lo)
{
    const int tid = threadIdx.x;        // tid = t*64 + l
    const int l = tid & 63, t = tid >> 6;
    #pragma unroll
    for (int j = 0; j < 8; ++j) {
        const int k = (l >> 4) * 8 + j;
        const int d = t * 16 + (l & 15);
        const float w = We[k * HD + d];
        const unsigned short hi = f32_to_bf16_rne(w);
        const unsigned short lo = f32_to_bf16_rne(w - bf16_bits_to_f32(hi));
        frag_hi[tid * 8 + j] = hi;
        frag_lo[tid * 8 + j] = lo;
    }
}

// ---------------------------------------------------------------------------
// Kernel 2: degree histogram over src + per-edge rank (coalesced write).
// ---------------------------------------------------------------------------
__global__ __launch_bounds__(256) void hist_rank_kernel(
    const int* __restrict__ ei, int* __restrict__ deg, int* __restrict__ rank)
{
    const int e = blockIdx.x * blockDim.x + threadIdx.x;
    if (e >= NE_) return;
    rank[e] = atomicAdd(&deg[ei[e]], 1);
}

// ---------------------------------------------------------------------------
// Kernel 3: exclusive scan of deg -> off (shfl-based, 2 barriers)
// ---------------------------------------------------------------------------
__global__ __launch_bounds__(SCAN_T) void scan_kernel(
    const int* __restrict__ deg, int* __restrict__ off)
{
    __shared__ int wsum[16];
    const int t = threadIdx.x;
    const int lane = t & 63, w = t >> 6;
    const int base = t * CHUNK;
    int v[CHUNK];
    int sum = 0;
    #pragma unroll
    for (int i = 0; i < CHUNK; ++i) {
        const int idx = base + i;
        v[i] = (idx < NN) ? deg[idx] : 0;
        sum += v[i];
    }
    int incl = sum;
    #pragma unroll
    for (int dlt = 1; dlt < 64; dlt <<= 1) {
        const int nb = __shfl_up(incl, dlt, 64);
        if (lane >= dlt) incl += nb;
    }
    if (lane == 63) wsum[w] = incl;
    __syncthreads();
    if (w == 0) {
        const int val = (lane < 16) ? wsum[lane] : 0;
        int wi = val;
        #pragma unroll
        for (int dlt = 1; dlt < 16; dlt <<= 1) {
            const int nb = __shfl_up(wi, dlt, 64);
            if (lane >= dlt) wi += nb;
        }
        if (lane < 16) wsum[lane] = wi - val;   // exclusive wave prefix
    }
    __syncthreads();
    int run = wsum[w] + (incl - sum);
    #pragma unroll
    for (int i = 0; i < CHUNK; ++i) {
        const int idx = base + i;
        if (idx < NN) { off[idx] = run; run += v[i]; }
    }
}

// ---------------------------------------------------------------------------
// Kernel 4: ee via split-We bf16 MFMA (ea rounded once); plain 16B scatter.
//   ALL accumulators are named scalars (macro-generated) -- no allocas, so
//   nothing gets promoted to LDS (R6: float part[4][4] became 16KB LDS/block
//   with 160K bank conflicts).
//   pos = off[src] + rank[e]; payload = (dst, ee0-ee3, ee1-ee3, ee2-ee3).
// ---------------------------------------------------------------------------
__global__ __launch_bounds__(256) void ee_scatter_kernel(
    const float* __restrict__ ea,
    const unsigned short* __restrict__ frag_hi,
    const unsigned short* __restrict__ frag_lo,
    const float* __restrict__ be,
    const int* __restrict__ ei,
    const int* __restrict__ off, const int* __restrict__ rank,
    float4* __restrict__ pay)
{
    const int lane = threadIdx.x & 63;
    const int wave = threadIdx.x >> 6;
    const int base = blockIdx.x * 256 + wave * 64;   // 64 edges per wave

    // this lane's edge metadata (all coalesced; off[] is a 40KB hot gather)
    const int src  = ei[base + lane];
    const int dstn = ei[NE_ + base + lane];
    const int pos  = off[src] + rank[base + lane];

    // ea B-fragments (4 tiles of 16 edges), bf16 single-rounding
    const int erow = lane & 15;
    const int kc = lane >> 4;          // k-chunk 0..3
    bf16x8 ah0, ah1, ah2, ah3;
#define LOAD_A(AT, VAR) { \
    const float* ar = ea + (size_t)(base + AT * 16 + erow) * E_DIM + kc * 8; \
    const float4 a0 = *reinterpret_cast<const float4*>(ar); \
    const float4 a1 = *reinterpret_cast<const float4*>(ar + 4); \
    VAR[0] = (short)f32_to_bf16_rne(a0.x); VAR[1] = (short)f32_to_bf16_rne(a0.y); \
    VAR[2] = (short)f32_to_bf16_rne(a0.z); VAR[3] = (short)f32_to_bf16_rne(a0.w); \
    VAR[4] = (short)f32_to_bf16_rne(a1.x); VAR[5] = (short)f32_to_bf16_rne(a1.y); \
    VAR[6] = (short)f32_to_bf16_rne(a1.z); VAR[7] = (short)f32_to_bf16_rne(a1.w); }
    LOAD_A(0, ah0) LOAD_A(1, ah1) LOAD_A(2, ah2) LOAD_A(3, ah3)
#undef LOAD_A

    // p{at}{h}: partial sum of ef^2 over this lane's d-rows, named scalars
    float p00 = 0.f, p01 = 0.f, p02 = 0.f, p03 = 0.f;
    float p10 = 0.f, p11 = 0.f, p12 = 0.f, p13 = 0.f;
    float p20 = 0.f, p21 = 0.f, p22 = 0.f, p23 = 0.f;
    float p30 = 0.f, p31 = 0.f, p32 = 0.f, p33 = 0.f;

#define AT_BODY(AT, H, WHI, WLO, BE4) { \
    f32x4 acc = {0.f, 0.f, 0.f, 0.f}; \
    acc = __builtin_amdgcn_mfma_f32_16x16x32_bf16(WLO, ah##AT, acc, 0, 0, 0); \
    acc = __builtin_amdgcn_mfma_f32_16x16x32_bf16(WHI, ah##AT, acc, 0, 0, 0); \
    const float e0 = acc[0] + BE4.x, e1 = acc[1] + BE4.y; \
    const float e2 = acc[2] + BE4.z, e3 = acc[3] + BE4.w; \
    p##AT##H += e0 * e0 + e1 * e1 + e2 * e2 + e3 * e3; }

#define TILE(T, H) { \
    const bf16x8 whi = *reinterpret_cast<const bf16x8*>(frag_hi + ((T * 64 + lane) << 3)); \
    const bf16x8 wlo = *reinterpret_cast<const bf16x8*>(frag_lo + ((T * 64 + lane) << 3)); \
    const float4 be4 = *reinterpret_cast<const float4*>(be + T * 16 + ((lane >> 4) << 2)); \
    AT_BODY(0, H, whi, wlo, be4) AT_BODY(1, H, whi, wlo, be4) \
    AT_BODY(2, H, whi, wlo, be4) AT_BODY(3, H, whi, wlo, be4) }

    TILE(0, 0) TILE(1, 0) TILE(2, 1) TILE(3, 1)
    TILE(4, 2) TILE(5, 2) TILE(6, 3) TILE(7, 3)
#undef TILE
#undef AT_BODY

    // reduce over the 4 row-groups (lanes l, l^16, l^32, l^48)
#define RED(AT, H) \
    float r##AT##H = p##AT##H; \
    r##AT##H += __shfl_xor(r##AT##H, 16, 64); \
    r##AT##H += __shfl_xor(r##AT##H, 32, 64);
    RED(0, 0) RED(0, 1) RED(0, 2) RED(0, 3)
    RED(1, 0) RED(1, 1) RED(1, 2) RED(1, 3)
    RED(2, 0) RED(2, 1) RED(2, 2) RED(2, 3)
    RED(3, 0) RED(3, 1) RED(3, 2) RED(3, 3)
#undef RED

    // lane l owns edge base+l  (tile at = l>>4, edge-in-tile = l&15)
    const int at4 = lane >> 4;
#define SEL(H) ((at4 & 2) ? ((at4 & 1) ? r3##H : r2##H) : ((at4 & 1) ? r1##H : r0##H))
    const float w0 = SEL(0), w1 = SEL(1), w2 = SEL(2), w3 = SEL(3);
#undef SEL

    pay[pos] = make_float4(__int_as_float(dstn), w0 - w3, w1 - w3, w2 - w3);
}

// ---------------------------------------------------------------------------
// Kernel 5: fused score+softmax+aggregate, CSR order.
//   block = node n, 8 groups of 32 lanes; group = one edge/iter.
//   lane o: h = o>>3; qk partial on dims o*4..o*4+3 (Kb bf16); 6-shuffle
//   reduce+bcast; softmax; acc += alpha . PTb[dst] (bf16).
// ---------------------------------------------------------------------------
__global__ __launch_bounds__(256) void fused_gather_kernel(
    const int* __restrict__ off, const int* __restrict__ deg,
    const float4* __restrict__ pay,
    const float* __restrict__ Q, const unsigned short* __restrict__ Kb,
    const unsigned short* __restrict__ PTb, const float* __restrict__ bo,
    float* __restrict__ out)
{
    __shared__ float red[8][OUT_DIM];
    const int n = blockIdx.x;
    const int d = deg[n];
    const int start = off[n];
    const int tid = threadIdx.x;
    const int g = tid >> 5, o = tid & 31;
    const int h = o >> 3;
    const float scale = 0.17677669529663687f;  // 1/sqrt(32)

    const float4 q4 = *reinterpret_cast<const float4*>(Q + (size_t)n * HD + o * 4);

    float acc = 0.f;
    float4 pc = make_float4(0.f, 0.f, 0.f, 0.f);
    if (g < d) pc = pay[start + g];

    for (int i = g; i < d; i += 8) {
        float4 pn = make_float4(0.f, 0.f, 0.f, 0.f);
        if (i + 8 < d) pn = pay[start + i + 8];   // prefetch next iter

        const int dst = __float_as_int(pc.x);
        const ushort4 kb = *reinterpret_cast<const ushort4*>(Kb + (size_t)dst * HD + o * 4);
        const ushort4 pb = *reinterpret_cast<const ushort4*>(PTb + (size_t)dst * HD + o * 4);

        float p =           q4.x * bf16_bits_to_f32(kb.x);
        p = fmaf(q4.y, bf16_bits_to_f32(kb.y), p);
        p = fmaf(q4.z, bf16_bits_to_f32(kb.z), p);
        p = fmaf(q4.w, bf16_bits_to_f32(kb.w), p);
        p += __shfl_xor(p, 1, 64);
        p += __shfl_xor(p, 2, 64);
        p += __shfl_xor(p, 4, 64);
        // broadcast all 4 head sums to every lane
        const float b  = __shfl_xor(p, 8, 64);
        const float e0 = (h & 1) ? b : p;
        const float e1 = (h & 1) ? p : b;
        const float o0 = __shfl_xor(e0, 16, 64);
        const float o1 = __shfl_xor(e1, 16, 64);
        const float qk0 = (h & 2) ? o0 : e0;
        const float qk1 = (h & 2) ? o1 : e1;
        const float qk2 = (h & 2) ? e0 : o0;
        const float qk3 = (h & 2) ? e1 : o1;

        const float s0 = (qk0 + pc.y) * scale;
        const float s1 = (qk1 + pc.z) * scale;
        const float s2 = (qk2 + pc.w) * scale;
        const float s3 = qk3 * scale;
        const float mx = fmaxf(fmaxf(s0, s1), fmaxf(s2, s3));
        const float a0 = __expf(s0 - mx), a1 = __expf(s1 - mx);
        const float a2 = __expf(s2 - mx), a3 = __expf(s3 - mx);
        const float inv = 1.f / (a0 + a1 + a2 + a3);
        const float c = fmaf(a0, bf16_bits_to_f32(pb.x),
                        fmaf(a1, bf16_bits_to_f32(pb.y),
                        fmaf(a2, bf16_bits_to_f32(pb.z),
                             a3 * bf16_bits_to_f32(pb.w))));
        acc = fmaf(c, inv, acc);
        pc = pn;
    }
    red[g][o] = acc;
    __syncthreads();
    if (tid < 32) {
        const float s = red[0][o] + red[1][o] + red[2][o] + red[3][o]
                      + red[4][o] + red[5][o] + red[6][o] + red[7][o];
        out[(size_t)n * OUT_DIM + o] = (d > 0) ? (s / (float)d + bo[o]) : 0.f;
    }
}

extern "C" void kernel_launch(void* const* d_in, const int* in_sizes, int n_in,
                              void* d_out, int out_size, void* d_ws, size_t ws_size,
                              hipStream_t stream)
{
    const float* x   = (const float*)d_in[0];
    const int*   ei  = (const int*)  d_in[1];
    const float* ea  = (const float*)d_in[2];
    const float* Wq  = (const float*)d_in[3];
    const float* bq  = (const float*)d_in[4];
    const float* Wk  = (const float*)d_in[5];
    const float* bk  = (const float*)d_in[6];
    const float* Wv  = (const float*)d_in[7];
    const float* bv  = (const float*)d_in[8];
    const float* We  = (const float*)d_in[9];
    const float* be  = (const float*)d_in[10];
    const float* Wo  = (const float*)d_in[11];
    const float* bo  = (const float*)d_in[12];
    float* out = (float*)d_out;

    // workspace layout (16B-aligned chunks)
    float*  Q   = (float*)d_ws;                          // NN*HD f32
    float4* pay = (float4*)(Q + (size_t)NN * HD);        // NE_ float4
    unsigned short* Kb  = (unsigned short*)(pay + NE_);  // NN*HD bf16
    unsigned short* PTb = Kb + (size_t)NN * HD;          // NN*HD bf16
    unsigned short* frag_hi = PTb + (size_t)NN * HD;     // 4096
    unsigned short* frag_lo = frag_hi + 8 * 64 * 8;      // 4096
    int* rank = (int*)(frag_lo + 8 * 64 * 8);            // NE_
    int* deg  = rank + NE_;                              // NN
    int* off  = deg + NN;                                // NN

    hipMemsetAsync(deg, 0, NN * sizeof(int), stream);

    qkvp_kernel<<<NN / NB, 256, 0, stream>>>(x, Wq, bq, Wk, bk, Wv, bv, Wo, Q, Kb, PTb);
    wet_kernel<<<1, 512, 0, stream>>>(We, frag_hi, frag_lo);
    hist_rank_kernel<<<(NE_ + 255) / 256, 256, 0, stream>>>(ei, deg, rank);
    scan_kernel<<<1, SCAN_T, 0, stream>>>(deg, off);
    ee_scatter_kernel<<<NE_ / 256, 256, 0, stream>>>(ea, frag_hi, frag_lo, be,
                                                     ei, off, rank, pay);
    fused_gather_kernel<<<NN, 256, 0, stream>>>(off, deg, pay, Q, Kb, PTb, bo, out);
}

// Round 8
// 161.255 us; speedup vs baseline: 3.1732x; 1.1780x over previous
//
#include <hip/hip_runtime.h>

#define NN      10000
#define IN_DIM  128
#define E_DIM   32
#define NH      4
#define DH      32
#define HD      128   // NH*DH
#define NE_     640000
#define OUT_DIM 32
#define SCAN_T  1024
#define CHUNK   10    // SCAN_T*CHUNK >= NN
#define NTILES  (NN / 16)        // 625 node-tiles
#define NTASKS  (NTILES * 3)     // x 3 col-groups (Q, K, P)

typedef __attribute__((ext_vector_type(8))) short bf16x8;
typedef __attribute__((ext_vector_type(4))) float f32x4;

static __device__ __forceinline__ unsigned short f32_to_bf16_rne(float f) {
    unsigned u = __float_as_uint(f);
    return (unsigned short)((u + 0x7fffu + ((u >> 16) & 1u)) >> 16);
}
static __device__ __forceinline__ float bf16_bits_to_f32(unsigned short h) {
    return __uint_as_float(((unsigned)h) << 16);
}

// ---------------------------------------------------------------------------
// Kernel 0: Wp[i][o*4+h] = sum_d Wv[i][h*32+d] * Wo[(h*32+d)*32+o]
//           bp[o*4+h]    = sum_d bv[h*32+d]    * Wo[(h*32+d)*32+o]
// (folds the out-Linear through V so node GEMM emits PT directly)
// ---------------------------------------------------------------------------
__global__ __launch_bounds__(256) void wp_kernel(
    const float* __restrict__ Wv, const float* __restrict__ bv,
    const float* __restrict__ Wo,
    float* __restrict__ Wp, float* __restrict__ bp)
{
    const int f = blockIdx.x * 256 + threadIdx.x;   // 16384 entries
    if (f >= IN_DIM * HD) return;
    const int i = f >> 7, flat = f & 127;
    const int h = flat & 3, o = flat >> 2;
    float acc = 0.f;
    #pragma unroll 8
    for (int d = 0; d < DH; ++d)
        acc = fmaf(Wv[i * HD + h * DH + d], Wo[(h * DH + d) * OUT_DIM + o], acc);
    Wp[f] = acc;
    if (f < HD) {
        const int h2 = f & 3, o2 = f >> 2;
        float b = 0.f;
        #pragma unroll 8
        for (int d = 0; d < DH; ++d)
            b = fmaf(bv[h2 * DH + d], Wo[(h2 * DH + d) * OUT_DIM + o2], b);
        bp[f] = b;
    }
}

// ---------------------------------------------------------------------------
// Kernel 0b: pre-swizzled hi/lo A-fragments of Wall = [Wq | Wk | Wp].
//   global col tile t (0..23), k-step s (0..3), lane l, elem j:
//   W[k = s*32 + (l>>4)*8 + j][col = (t&7)*16 + (l&15)]
//   -> wfh/wfl[((t*4+s)*64 + l)*8 + j]
// ---------------------------------------------------------------------------
__global__ __launch_bounds__(512) void wfrag_kernel(
    const float* __restrict__ Wq, const float* __restrict__ Wk,
    const float* __restrict__ Wp,
    unsigned short* __restrict__ wfh, unsigned short* __restrict__ wfl)
{
    const int tid = blockIdx.x * 512 + threadIdx.x;   // (t*4+s)*64 + l
    if (tid >= 24 * 4 * 64) return;
    const int l = tid & 63;
    const int ts = tid >> 6;
    const int s = ts & 3, t = ts >> 2;
    const float* __restrict__ W = (t < 8) ? Wq : (t < 16) ? Wk : Wp;
    const int col = (t & 7) * 16 + (l & 15);
    #pragma unroll
    for (int j = 0; j < 8; ++j) {
        const int k = s * 32 + (l >> 4) * 8 + j;
        const float w = W[k * HD + col];
        const unsigned short hi = f32_to_bf16_rne(w);
        wfh[tid * 8 + j] = hi;
        wfl[tid * 8 + j] = f32_to_bf16_rne(w - bf16_bits_to_f32(hi));
    }
}

// ---------------------------------------------------------------------------
// Kernel 1: node GEMM [Q|Kb|PTb] = x @ [Wq|Wk|Wp] + bias via split-bf16 MFMA.
//   wave task = (node-tile nt, col-group cg); 16 nodes x 128 cols per task.
//   D layout (verified via ee_kernel): col(N)=node=lane&15,
//   row(M)=out-col j=(lane>>4)*4+reg. All frags/accs are named scalars.
// ---------------------------------------------------------------------------
__global__ __launch_bounds__(256) void qkvp_mfma_kernel(
    const float* __restrict__ x,
    const unsigned short* __restrict__ wfh, const unsigned short* __restrict__ wfl,
    const float* __restrict__ bq, const float* __restrict__ bk,
    const float* __restrict__ bp,
    float* __restrict__ Q, unsigned short* __restrict__ Kb,
    unsigned short* __restrict__ PTb)
{
    const int lane = threadIdx.x & 63;
    const int wave = threadIdx.x >> 6;
    const int task = blockIdx.x * 4 + wave;
    if (task >= NTASKS) return;
    const int nt = task / 3, cg = task - nt * 3;
    const int node = nt * 16 + (lane & 15);
    const int kc = lane >> 4;          // 0..3

    // x B-fragments: 4 k-steps, hi/lo split (named)
    bf16x8 xh0, xl0, xh1, xl1, xh2, xl2, xh3, xl3;
#define SPL(VH, VL, I, VAL) { \
    const unsigned short hh = f32_to_bf16_rne(VAL); \
    VH[I] = (short)hh; VL[I] = (short)f32_to_bf16_rne((VAL) - bf16_bits_to_f32(hh)); }
#define LOAD_X(S, VH, VL) { \
    const float* xr = x + (size_t)node * IN_DIM + (S) * 32 + kc * 8; \
    const float4 a0 = *reinterpret_cast<const float4*>(xr); \
    const float4 a1 = *reinterpret_cast<const float4*>(xr + 4); \
    SPL(VH, VL, 0, a0.x) SPL(VH, VL, 1, a0.y) SPL(VH, VL, 2, a0.z) SPL(VH, VL, 3, a0.w) \
    SPL(VH, VL, 4, a1.x) SPL(VH, VL, 5, a1.y) SPL(VH, VL, 6, a1.z) SPL(VH, VL, 7, a1.w) }
    LOAD_X(0, xh0, xl0) LOAD_X(1, xh1, xl1) LOAD_X(2, xh2, xl2) LOAD_X(3, xh3, xl3)
#undef LOAD_X
#undef SPL

    const float* __restrict__ bb = (cg == 0) ? bq : (cg == 1) ? bk : bp;

#define KSTEP(S, FB, FB2, XH, XL) { \
    const bf16x8 wh = *reinterpret_cast<const bf16x8*>((FB)  + (S) * 64 * 8); \
    const bf16x8 wl = *reinterpret_cast<const bf16x8*>((FB2) + (S) * 64 * 8); \
    acc = __builtin_amdgcn_mfma_f32_16x16x32_bf16(wh, XH, acc, 0, 0, 0); \
    acc = __builtin_amdgcn_mfma_f32_16x16x32_bf16(wh, XL, acc, 0, 0, 0); \
    acc = __builtin_amdgcn_mfma_f32_16x16x32_bf16(wl, XH, acc, 0, 0, 0); }

#define TILE(TLOC) { \
    const unsigned short* fb  = wfh + ((((cg * 8 + TLOC) * 4) * 64 + lane) << 3); \
    const unsigned short* fb2 = wfl + ((((cg * 8 + TLOC) * 4) * 64 + lane) << 3); \
    f32x4 acc = {0.f, 0.f, 0.f, 0.f}; \
    KSTEP(0, fb, fb2, xh0, xl0) KSTEP(1, fb, fb2, xh1, xl1) \
    KSTEP(2, fb, fb2, xh2, xl2) KSTEP(3, fb, fb2, xh3, xl3) \
    const float4 b4 = *reinterpret_cast<const float4*>(bb + (TLOC) * 16 + (kc << 2)); \
    const float o0 = acc[0] + b4.x, o1 = acc[1] + b4.y; \
    const float o2 = acc[2] + b4.z, o3 = acc[3] + b4.w; \
    const int j0 = (TLOC) * 16 + (kc << 2); \
    if (cg == 0) { \
        *reinterpret_cast<float4*>(Q + (size_t)node * HD + j0) = \
            make_float4(o0, o1, o2, o3); \
    } else { \
        unsigned short* dp = ((cg == 1) ? Kb : PTb) + (size_t)node * HD + j0; \
        *reinterpret_cast<ushort4*>(dp) = make_ushort4( \
            f32_to_bf16_rne(o0), f32_to_bf16_rne(o1), \
            f32_to_bf16_rne(o2), f32_to_bf16_rne(o3)); \
    } }

    TILE(0) TILE(1) TILE(2) TILE(3) TILE(4) TILE(5) TILE(6) TILE(7)
#undef TILE
#undef KSTEP
}

// ---------------------------------------------------------------------------
// Kernel 1b: pre-swizzled bf16 hi/lo MFMA A-fragments of We (for ee_scatter).
// ---------------------------------------------------------------------------
__global__ __launch_bounds__(512) void wet_kernel(
    const float* __restrict__ We,
    unsigned short* __restrict__ frag_hi, unsigned short* __restrict__ frag_lo)
{
    const int tid = threadIdx.x;        // tid = t*64 + l
    const int l = tid & 63, t = tid >> 6;
    #pragma unroll
    for (int j = 0; j < 8; ++j) {
        const int k = (l >> 4) * 8 + j;
        const int d = t * 16 + (l & 15);
        const float w = We[k * HD + d];
        const unsigned short hi = f32_to_bf16_rne(w);
        frag_hi[tid * 8 + j] = hi;
        frag_lo[tid * 8 + j] = f32_to_bf16_rne(w - bf16_bits_to_f32(hi));
    }
}

// ---------------------------------------------------------------------------
// Kernel 2: degree histogram over src + per-edge rank (coalesced write).
// ---------------------------------------------------------------------------
__global__ __launch_bounds__(256) void hist_rank_kernel(
    const int* __restrict__ ei, int* __restrict__ deg, int* __restrict__ rank)
{
    const int e = blockIdx.x * blockDim.x + threadIdx.x;
    if (e >= NE_) return;
    rank[e] = atomicAdd(&deg[ei[e]], 1);
}

// ---------------------------------------------------------------------------
// Kernel 3: exclusive scan of deg -> off (shfl-based, 2 barriers)
// ---------------------------------------------------------------------------
__global__ __launch_bounds__(SCAN_T) void scan_kernel(
    const int* __restrict__ deg, int* __restrict__ off)
{
    __shared__ int wsum[16];
    const int t = threadIdx.x;
    const int lane = t & 63, w = t >> 6;
    const int base = t * CHUNK;
    int v[CHUNK];
    int sum = 0;
    #pragma unroll
    for (int i = 0; i < CHUNK; ++i) {
        const int idx = base + i;
        v[i] = (idx < NN) ? deg[idx] : 0;
        sum += v[i];
    }
    int incl = sum;
    #pragma unroll
    for (int dlt = 1; dlt < 64; dlt <<= 1) {
        const int nb = __shfl_up(incl, dlt, 64);
        if (lane >= dlt) incl += nb;
    }
    if (lane == 63) wsum[w] = incl;
    __syncthreads();
    if (w == 0) {
        const int val = (lane < 16) ? wsum[lane] : 0;
        int wi = val;
        #pragma unroll
        for (int dlt = 1; dlt < 16; dlt <<= 1) {
            const int nb = __shfl_up(wi, dlt, 64);
            if (lane >= dlt) wi += nb;
        }
        if (lane < 16) wsum[lane] = wi - val;   // exclusive wave prefix
    }
    __syncthreads();
    int run = wsum[w] + (incl - sum);
    #pragma unroll
    for (int i = 0; i < CHUNK; ++i) {
        const int idx = base + i;
        if (idx < NN) { off[idx] = run; run += v[i]; }
    }
}

// ---------------------------------------------------------------------------
// Kernel 4: ee via split-We bf16 MFMA (ea rounded once); plain 16B scatter.
//   Named-scalar accumulators (R6: arrays got LDS-promoted).
//   pos = off[src] + rank[e]; payload = (dst, ee0-ee3, ee1-ee3, ee2-ee3).
// ---------------------------------------------------------------------------
__global__ __launch_bounds__(256) void ee_scatter_kernel(
    const float* __restrict__ ea,
    const unsigned short* __restrict__ frag_hi,
    const unsigned short* __restrict__ frag_lo,
    const float* __restrict__ be,
    const int* __restrict__ ei,
    const int* __restrict__ off, const int* __restrict__ rank,
    float4* __restrict__ pay)
{
    const int lane = threadIdx.x & 63;
    const int wave = threadIdx.x >> 6;
    const int base = blockIdx.x * 256 + wave * 64;   // 64 edges per wave

    const int src  = ei[base + lane];
    const int dstn = ei[NE_ + base + lane];
    const int pos  = off[src] + rank[base + lane];

    const int erow = lane & 15;
    const int kc = lane >> 4;          // k-chunk 0..3
    bf16x8 ah0, ah1, ah2, ah3;
#define LOAD_A(AT, VAR) { \
    const float* ar = ea + (size_t)(base + AT * 16 + erow) * E_DIM + kc * 8; \
    const float4 a0 = *reinterpret_cast<const float4*>(ar); \
    const float4 a1 = *reinterpret_cast<const float4*>(ar + 4); \
    VAR[0] = (short)f32_to_bf16_rne(a0.x); VAR[1] = (short)f32_to_bf16_rne(a0.y); \
    VAR[2] = (short)f32_to_bf16_rne(a0.z); VAR[3] = (short)f32_to_bf16_rne(a0.w); \
    VAR[4] = (short)f32_to_bf16_rne(a1.x); VAR[5] = (short)f32_to_bf16_rne(a1.y); \
    VAR[6] = (short)f32_to_bf16_rne(a1.z); VAR[7] = (short)f32_to_bf16_rne(a1.w); }
    LOAD_A(0, ah0) LOAD_A(1, ah1) LOAD_A(2, ah2) LOAD_A(3, ah3)
#undef LOAD_A

    float p00 = 0.f, p01 = 0.f, p02 = 0.f, p03 = 0.f;
    float p10 = 0.f, p11 = 0.f, p12 = 0.f, p13 = 0.f;
    float p20 = 0.f, p21 = 0.f, p22 = 0.f, p23 = 0.f;
    float p30 = 0.f, p31 = 0.f, p32 = 0.f, p33 = 0.f;

#define AT_BODY(AT, H, WHI, WLO, BE4) { \
    f32x4 acc = {0.f, 0.f, 0.f, 0.f}; \
    acc = __builtin_amdgcn_mfma_f32_16x16x32_bf16(WLO, ah##AT, acc, 0, 0, 0); \
    acc = __builtin_amdgcn_mfma_f32_16x16x32_bf16(WHI, ah##AT, acc, 0, 0, 0); \
    const float e0 = acc[0] + BE4.x, e1 = acc[1] + BE4.y; \
    const float e2 = acc[2] + BE4.z, e3 = acc[3] + BE4.w; \
    p##AT##H += e0 * e0 + e1 * e1 + e2 * e2 + e3 * e3; }

#define TILE(T, H) { \
    const bf16x8 whi = *reinterpret_cast<const bf16x8*>(frag_hi + ((T * 64 + lane) << 3)); \
    const bf16x8 wlo = *reinterpret_cast<const bf16x8*>(frag_lo + ((T * 64 + lane) << 3)); \
    const float4 be4 = *reinterpret_cast<const float4*>(be + T * 16 + ((lane >> 4) << 2)); \
    AT_BODY(0, H, whi, wlo, be4) AT_BODY(1, H, whi, wlo, be4) \
    AT_BODY(2, H, whi, wlo, be4) AT_BODY(3, H, whi, wlo, be4) }

    TILE(0, 0) TILE(1, 0) TILE(2, 1) TILE(3, 1)
    TILE(4, 2) TILE(5, 2) TILE(6, 3) TILE(7, 3)
#undef TILE
#undef AT_BODY

#define RED(AT, H) \
    float r##AT##H = p##AT##H; \
    r##AT##H += __shfl_xor(r##AT##H, 16, 64); \
    r##AT##H += __shfl_xor(r##AT##H, 32, 64);
    RED(0, 0) RED(0, 1) RED(0, 2) RED(0, 3)
    RED(1, 0) RED(1, 1) RED(1, 2) RED(1, 3)
    RED(2, 0) RED(2, 1) RED(2, 2) RED(2, 3)
    RED(3, 0) RED(3, 1) RED(3, 2) RED(3, 3)
#undef RED

    const int at4 = lane >> 4;
#define SEL(H) ((at4 & 2) ? ((at4 & 1) ? r3##H : r2##H) : ((at4 & 1) ? r1##H : r0##H))
    const float w0 = SEL(0), w1 = SEL(1), w2 = SEL(2), w3 = SEL(3);
#undef SEL

    pay[pos] = make_float4(__int_as_float(dstn), w0 - w3, w1 - w3, w2 - w3);
}

// ---------------------------------------------------------------------------
// Kernel 5: fused score+softmax+aggregate, CSR order.
// ---------------------------------------------------------------------------
__global__ __launch_bounds__(256) void fused_gather_kernel(
    const int* __restrict__ off, const int* __restrict__ deg,
    const float4* __restrict__ pay,
    const float* __restrict__ Q, const unsigned short* __restrict__ Kb,
    const unsigned short* __restrict__ PTb, const float* __restrict__ bo,
    float* __restrict__ out)
{
    __shared__ float red[8][OUT_DIM];
    const int n = blockIdx.x;
    const int d = deg[n];
    const int start = off[n];
    const int tid = threadIdx.x;
    const int g = tid >> 5, o = tid & 31;
    const int h = o >> 3;
    const float scale = 0.17677669529663687f;  // 1/sqrt(32)

    const float4 q4 = *reinterpret_cast<const float4*>(Q + (size_t)n * HD + o * 4);

    float acc = 0.f;
    float4 pc = make_float4(0.f, 0.f, 0.f, 0.f);
    if (g < d) pc = pay[start + g];

    for (int i = g; i < d; i += 8) {
        float4 pn = make_float4(0.f, 0.f, 0.f, 0.f);
        if (i + 8 < d) pn = pay[start + i + 8];   // prefetch next iter

        const int dst = __float_as_int(pc.x);
        const ushort4 kb = *reinterpret_cast<const ushort4*>(Kb + (size_t)dst * HD + o * 4);
        const ushort4 pb = *reinterpret_cast<const ushort4*>(PTb + (size_t)dst * HD + o * 4);

        float p =           q4.x * bf16_bits_to_f32(kb.x);
        p = fmaf(q4.y, bf16_bits_to_f32(kb.y), p);
        p = fmaf(q4.z, bf16_bits_to_f32(kb.z), p);
        p = fmaf(q4.w, bf16_bits_to_f32(kb.w), p);
        p += __shfl_xor(p, 1, 64);
        p += __shfl_xor(p, 2, 64);
        p += __shfl_xor(p, 4, 64);
        const float b  = __shfl_xor(p, 8, 64);
        const float e0 = (h & 1) ? b : p;
        const float e1 = (h & 1) ? p : b;
        const float o0 = __shfl_xor(e0, 16, 64);
        const float o1 = __shfl_xor(e1, 16, 64);
        const float qk0 = (h & 2) ? o0 : e0;
        const float qk1 = (h & 2) ? o1 : e1;
        const float qk2 = (h & 2) ? e0 : o0;
        const float qk3 = (h & 2) ? e1 : o1;

        const float s0 = (qk0 + pc.y) * scale;
        const float s1 = (qk1 + pc.z) * scale;
        const float s2 = (qk2 + pc.w) * scale;
        const float s3 = qk3 * scale;
        const float mx = fmaxf(fmaxf(s0, s1), fmaxf(s2, s3));
        const float a0 = __expf(s0 - mx), a1 = __expf(s1 - mx);
        const float a2 = __expf(s2 - mx), a3 = __expf(s3 - mx);
        const float inv = 1.f / (a0 + a1 + a2 + a3);
        const float c = fmaf(a0, bf16_bits_to_f32(pb.x),
                        fmaf(a1, bf16_bits_to_f32(pb.y),
                        fmaf(a2, bf16_bits_to_f32(pb.z),
                             a3 * bf16_bits_to_f32(pb.w))));
        acc = fmaf(c, inv, acc);
        pc = pn;
    }
    red[g][o] = acc;
    __syncthreads();
    if (tid < 32) {
        const float s = red[0][o] + red[1][o] + red[2][o] + red[3][o]
                      + red[4][o] + red[5][o] + red[6][o] + red[7][o];
        out[(size_t)n * OUT_DIM + o] = (d > 0) ? (s / (float)d + bo[o]) : 0.f;
    }
}

extern "C" void kernel_launch(void* const* d_in, const int* in_sizes, int n_in,
                              void* d_out, int out_size, void* d_ws, size_t ws_size,
                              hipStream_t stream)
{
    const float* x   = (const float*)d_in[0];
    const int*   ei  = (const int*)  d_in[1];
    const float* ea  = (const float*)d_in[2];
    const float* Wq  = (const float*)d_in[3];
    const float* bq  = (const float*)d_in[4];
    const float* Wk  = (const float*)d_in[5];
    const float* bk  = (const float*)d_in[6];
    const float* Wv  = (const float*)d_in[7];
    const float* bv  = (const float*)d_in[8];
    const float* We  = (const float*)d_in[9];
    const float* be  = (const float*)d_in[10];
    const float* Wo  = (const float*)d_in[11];
    const float* bo  = (const float*)d_in[12];
    float* out = (float*)d_out;

    // workspace layout (16B-aligned chunks)
    float*  Q   = (float*)d_ws;                          // NN*HD f32
    float4* pay = (float4*)(Q + (size_t)NN * HD);        // NE_ float4
    float*  Wp  = (float*)(pay + NE_);                   // IN_DIM*HD f32
    float*  bp  = Wp + IN_DIM * HD;                      // HD f32
    unsigned short* Kb  = (unsigned short*)(bp + HD);    // NN*HD bf16
    unsigned short* PTb = Kb + (size_t)NN * HD;          // NN*HD bf16
    unsigned short* wefh = PTb + (size_t)NN * HD;        // 4096
    unsigned short* wefl = wefh + 8 * 64 * 8;            // 4096
    unsigned short* wfh  = wefl + 8 * 64 * 8;            // 24*4*64*8 = 49152
    unsigned short* wfl  = wfh + 24 * 4 * 64 * 8;        // 49152
    int* rank = (int*)(wfl + 24 * 4 * 64 * 8);           // NE_
    int* deg  = rank + NE_;                              // NN
    int* off  = deg + NN;                                // NN

    hipMemsetAsync(deg, 0, NN * sizeof(int), stream);

    wp_kernel<<<(IN_DIM * HD + 255) / 256, 256, 0, stream>>>(Wv, bv, Wo, Wp, bp);
    wfrag_kernel<<<12, 512, 0, stream>>>(Wq, Wk, Wp, wfh, wfl);
    wet_kernel<<<1, 512, 0, stream>>>(We, wefh, wefl);
    hist_rank_kernel<<<(NE_ + 255) / 256, 256, 0, stream>>>(ei, deg, rank);
    scan_kernel<<<1, SCAN_T, 0, stream>>>(deg, off);
    qkvp_mfma_kernel<<<(NTASKS + 3) / 4, 256, 0, stream>>>(x, wfh, wfl, bq, bk, bp,
                                                           Q, Kb, PTb);
    ee_scatter_kernel<<<NE_ / 256, 256, 0, stream>>>(ea, wefh, wefl, be,
                                                     ei, off, rank, pay);
    fused_gather_kernel<<<NN, 256, 0, stream>>>(off, deg, pay, Q, Kb, PTb, bo, out);
}

// Round 9
// 133.990 us; speedup vs baseline: 3.8189x; 1.2035x over previous
//
#include <hip/hip_runtime.h>

#define NN      10000
#define IN_DIM  128
#define E_DIM   32
#define NH      4
#define DH      32
#define HD      128   // NH*DH
#define NE_     640000
#define OUT_DIM 32
#define SCAN_T  1024
#define CHUNK   10    // SCAN_T*CHUNK >= NN
#define NTILES  (NN / 16)        // 625 node-tiles
#define NTASKS  (NTILES * 3)     // x 3 col-groups (Q, K, P)
#define QKVP_BLKS  469           // ceil(NTASKS/4)
#define HIST_BLKS  (NE_ / 256)   // 2500
#define EE_BLKS    (NE_ / 256)   // 2500

typedef __attribute__((ext_vector_type(8))) short bf16x8;
typedef __attribute__((ext_vector_type(4))) float f32x4;

static __device__ __forceinline__ unsigned short f32_to_bf16_rne(float f) {
    unsigned u = __float_as_uint(f);
    return (unsigned short)((u + 0x7fffu + ((u >> 16) & 1u)) >> 16);
}
static __device__ __forceinline__ float bf16_bits_to_f32(unsigned short h) {
    return __uint_as_float(((unsigned)h) << 16);
}

// ---------------------------------------------------------------------------
// Kernel A (prep + hist, block-range dispatch; all parts independent):
//  blocks [0,24):   wfrag -- hi/lo A-fragments of [Wq|Wk|Wp], Wp computed
//                   inline (Wp[k][col] = sum_d Wv[k][h*32+d]*Wo[(h*32+d)*32+o])
//  blocks [24,26):  wet   -- hi/lo A-fragments of We
//  block  26:       bp[flat] = sum_d bv[h*32+d]*Wo[..o],  flat = o*4+h
//  blocks [27,...): hist_rank -- deg histogram + per-edge rank
// ---------------------------------------------------------------------------
__global__ __launch_bounds__(256) void prep_kernel(
    const float* __restrict__ Wq, const float* __restrict__ Wk,
    const float* __restrict__ Wv, const float* __restrict__ Wo,
    const float* __restrict__ bv, const float* __restrict__ We,
    const int*   __restrict__ ei,
    unsigned short* __restrict__ wfh, unsigned short* __restrict__ wfl,
    unsigned short* __restrict__ wefh, unsigned short* __restrict__ wefl,
    float* __restrict__ bp,
    int* __restrict__ deg, int* __restrict__ rank)
{
    const int blk = blockIdx.x;
    const int t = threadIdx.x;

    if (blk < 24) {                         // ---- wfrag (6144 threads) ----
        const int tid = blk * 256 + t;      // (tt*4+s)*64 + l
        const int l = tid & 63;
        const int ts = tid >> 6;
        const int s = ts & 3, tt = ts >> 2; // tt 0..23
        const int col = (tt & 7) * 16 + (l & 15);
        if (tt < 16) {
            const float* __restrict__ W = (tt < 8) ? Wq : Wk;
            #pragma unroll
            for (int j = 0; j < 8; ++j) {
                const int k = s * 32 + (l >> 4) * 8 + j;
                const float w = W[k * HD + col];
                const unsigned short hi = f32_to_bf16_rne(w);
                wfh[tid * 8 + j] = hi;
                wfl[tid * 8 + j] = f32_to_bf16_rne(w - bf16_bits_to_f32(hi));
            }
        } else {                            // Wp inline
            const int h = col & 3, oo = col >> 2;
            #pragma unroll
            for (int j = 0; j < 8; ++j) {
                const int k = s * 32 + (l >> 4) * 8 + j;
                float acc = 0.f;
                #pragma unroll
                for (int d2 = 0; d2 < DH; ++d2)
                    acc = fmaf(Wv[k * HD + h * DH + d2],
                               Wo[(h * DH + d2) * OUT_DIM + oo], acc);
                const unsigned short hi = f32_to_bf16_rne(acc);
                wfh[tid * 8 + j] = hi;
                wfl[tid * 8 + j] = f32_to_bf16_rne(acc - bf16_bits_to_f32(hi));
            }
        }
    } else if (blk < 26) {                  // ---- wet (512 threads) ----
        const int tid = (blk - 24) * 256 + t;
        const int l = tid & 63, tt = tid >> 6;
        #pragma unroll
        for (int j = 0; j < 8; ++j) {
            const int k = (l >> 4) * 8 + j;
            const int d = tt * 16 + (l & 15);
            const float w = We[k * HD + d];
            const unsigned short hi = f32_to_bf16_rne(w);
            wefh[tid * 8 + j] = hi;
            wefl[tid * 8 + j] = f32_to_bf16_rne(w - bf16_bits_to_f32(hi));
        }
    } else if (blk == 26) {                 // ---- bp ----
        if (t < HD) {
            const int h = t & 3, oo = t >> 2;
            float b = 0.f;
            #pragma unroll
            for (int d2 = 0; d2 < DH; ++d2)
                b = fmaf(bv[h * DH + d2], Wo[(h * DH + d2) * OUT_DIM + oo], b);
            bp[t] = b;
        }
    } else {                                // ---- hist_rank ----
        const int e = (blk - 27) * 256 + t;
        rank[e] = atomicAdd(&deg[ei[e]], 1);
    }
}

// ---------------------------------------------------------------------------
// Kernel B: exclusive scan of deg -> off (shfl-based, 2 barriers)
// ---------------------------------------------------------------------------
__global__ __launch_bounds__(SCAN_T) void scan_kernel(
    const int* __restrict__ deg, int* __restrict__ off)
{
    __shared__ int wsum[16];
    const int t = threadIdx.x;
    const int lane = t & 63, w = t >> 6;
    const int base = t * CHUNK;
    int v[CHUNK];
    int sum = 0;
    #pragma unroll
    for (int i = 0; i < CHUNK; ++i) {
        const int idx = base + i;
        v[i] = (idx < NN) ? deg[idx] : 0;
        sum += v[i];
    }
    int incl = sum;
    #pragma unroll
    for (int dlt = 1; dlt < 64; dlt <<= 1) {
        const int nb = __shfl_up(incl, dlt, 64);
        if (lane >= dlt) incl += nb;
    }
    if (lane == 63) wsum[w] = incl;
    __syncthreads();
    if (w == 0) {
        const int val = (lane < 16) ? wsum[lane] : 0;
        int wi = val;
        #pragma unroll
        for (int dlt = 1; dlt < 16; dlt <<= 1) {
            const int nb = __shfl_up(wi, dlt, 64);
            if (lane >= dlt) wi += nb;
        }
        if (lane < 16) wsum[lane] = wi - val;   // exclusive wave prefix
    }
    __syncthreads();
    int run = wsum[w] + (incl - sum);
    #pragma unroll
    for (int i = 0; i < CHUNK; ++i) {
        const int idx = base + i;
        if (idx < NN) { off[idx] = run; run += v[i]; }
    }
}

// ---------------------------------------------------------------------------
// Kernel C (mm, block-range dispatch):
//  blocks [0,QKVP_BLKS):  node GEMM [Q|K|PT] = x @ [Wq|Wk|Wp] + bias, split-
//    bf16 MFMA. K and PT write INTERLEAVED rows KPTb[n][o*8]={K[o*4..3],
//    PT[o*4..3]} so the gather kernel does ONE 16B load per lane per edge.
//  blocks [QKVP_BLKS,..): ee via split-We MFMA; plain 16B scatter to CSR slot.
//  All fragments/accumulators are named scalars (R6: arrays got LDS-promoted).
// ---------------------------------------------------------------------------
__global__ __launch_bounds__(256) void mm_kernel(
    const float* __restrict__ x,
    const unsigned short* __restrict__ wfh, const unsigned short* __restrict__ wfl,
    const float* __restrict__ bq, const float* __restrict__ bk,
    const float* __restrict__ bp,
    float* __restrict__ Q, unsigned short* __restrict__ KPTb,
    const float* __restrict__ ea,
    const unsigned short* __restrict__ wefh, const unsigned short* __restrict__ wefl,
    const float* __restrict__ be,
    const int* __restrict__ ei,
    const int* __restrict__ off, const int* __restrict__ rank,
    float4* __restrict__ pay)
{
    const int lane = threadIdx.x & 63;
    const int wave = threadIdx.x >> 6;

    if (blockIdx.x < QKVP_BLKS) {
        // ------------------- qkvp GEMM -------------------
        const int task = blockIdx.x * 4 + wave;
        if (task >= NTASKS) return;
        const int nt = task / 3, cg = task - nt * 3;
        const int node = nt * 16 + (lane & 15);
        const int kc = lane >> 4;          // 0..3

        bf16x8 xh0, xl0, xh1, xl1, xh2, xl2, xh3, xl3;
#define SPL(VH, VL, I, VAL) { \
    const unsigned short hh = f32_to_bf16_rne(VAL); \
    VH[I] = (short)hh; VL[I] = (short)f32_to_bf16_rne((VAL) - bf16_bits_to_f32(hh)); }
#define LOAD_X(S, VH, VL) { \
    const float* xr = x + (size_t)node * IN_DIM + (S) * 32 + kc * 8; \
    const float4 a0 = *reinterpret_cast<const float4*>(xr); \
    const float4 a1 = *reinterpret_cast<const float4*>(xr + 4); \
    SPL(VH, VL, 0, a0.x) SPL(VH, VL, 1, a0.y) SPL(VH, VL, 2, a0.z) SPL(VH, VL, 3, a0.w) \
    SPL(VH, VL, 4, a1.x) SPL(VH, VL, 5, a1.y) SPL(VH, VL, 6, a1.z) SPL(VH, VL, 7, a1.w) }
        LOAD_X(0, xh0, xl0) LOAD_X(1, xh1, xl1) LOAD_X(2, xh2, xl2) LOAD_X(3, xh3, xl3)
#undef LOAD_X
#undef SPL

        const float* __restrict__ bb = (cg == 0) ? bq : (cg == 1) ? bk : bp;

#define KSTEP(S, FB, FB2, XH, XL) { \
    const bf16x8 wh = *reinterpret_cast<const bf16x8*>((FB)  + (S) * 64 * 8); \
    const bf16x8 wl = *reinterpret_cast<const bf16x8*>((FB2) + (S) * 64 * 8); \
    acc = __builtin_amdgcn_mfma_f32_16x16x32_bf16(wh, XH, acc, 0, 0, 0); \
    acc = __builtin_amdgcn_mfma_f32_16x16x32_bf16(wh, XL, acc, 0, 0, 0); \
    acc = __builtin_amdgcn_mfma_f32_16x16x32_bf16(wl, XH, acc, 0, 0, 0); }

#define TILE(TLOC) { \
    const unsigned short* fb  = wfh + ((((cg * 8 + TLOC) * 4) * 64 + lane) << 3); \
    const unsigned short* fb2 = wfl + ((((cg * 8 + TLOC) * 4) * 64 + lane) << 3); \
    f32x4 acc = {0.f, 0.f, 0.f, 0.f}; \
    KSTEP(0, fb, fb2, xh0, xl0) KSTEP(1, fb, fb2, xh1, xl1) \
    KSTEP(2, fb, fb2, xh2, xl2) KSTEP(3, fb, fb2, xh3, xl3) \
    const float4 b4 = *reinterpret_cast<const float4*>(bb + (TLOC) * 16 + (kc << 2)); \
    const float o0 = acc[0] + b4.x, o1 = acc[1] + b4.y; \
    const float o2 = acc[2] + b4.z, o3 = acc[3] + b4.w; \
    const int j0 = (TLOC) * 16 + (kc << 2); \
    if (cg == 0) { \
        *reinterpret_cast<float4*>(Q + (size_t)node * HD + j0) = \
            make_float4(o0, o1, o2, o3); \
    } else { \
        unsigned short* dp = KPTb + (size_t)node * 256 + j0 * 2 + ((cg == 1) ? 0 : 4); \
        *reinterpret_cast<ushort4*>(dp) = make_ushort4( \
            f32_to_bf16_rne(o0), f32_to_bf16_rne(o1), \
            f32_to_bf16_rne(o2), f32_to_bf16_rne(o3)); \
    } }

        TILE(0) TILE(1) TILE(2) TILE(3) TILE(4) TILE(5) TILE(6) TILE(7)
#undef TILE
#undef KSTEP
        return;
    }

    // ------------------- ee + CSR scatter -------------------
    const int base = (blockIdx.x - QKVP_BLKS) * 256 + wave * 64;  // 64 edges/wave

    const int src  = ei[base + lane];
    const int dstn = ei[NE_ + base + lane];
    const int pos  = off[src] + rank[base + lane];

    const int erow = lane & 15;
    const int kc = lane >> 4;          // k-chunk 0..3
    bf16x8 ah0, ah1, ah2, ah3;
#define LOAD_A(AT, VAR) { \
    const float* ar = ea + (size_t)(base + AT * 16 + erow) * E_DIM + kc * 8; \
    const float4 a0 = *reinterpret_cast<const float4*>(ar); \
    const float4 a1 = *reinterpret_cast<const float4*>(ar + 4); \
    VAR[0] = (short)f32_to_bf16_rne(a0.x); VAR[1] = (short)f32_to_bf16_rne(a0.y); \
    VAR[2] = (short)f32_to_bf16_rne(a0.z); VAR[3] = (short)f32_to_bf16_rne(a0.w); \
    VAR[4] = (short)f32_to_bf16_rne(a1.x); VAR[5] = (short)f32_to_bf16_rne(a1.y); \
    VAR[6] = (short)f32_to_bf16_rne(a1.z); VAR[7] = (short)f32_to_bf16_rne(a1.w); }
    LOAD_A(0, ah0) LOAD_A(1, ah1) LOAD_A(2, ah2) LOAD_A(3, ah3)
#undef LOAD_A

    float p00 = 0.f, p01 = 0.f, p02 = 0.f, p03 = 0.f;
    float p10 = 0.f, p11 = 0.f, p12 = 0.f, p13 = 0.f;
    float p20 = 0.f, p21 = 0.f, p22 = 0.f, p23 = 0.f;
    float p30 = 0.f, p31 = 0.f, p32 = 0.f, p33 = 0.f;

#define AT_BODY(AT, H, WHI, WLO, BE4) { \
    f32x4 acc = {0.f, 0.f, 0.f, 0.f}; \
    acc = __builtin_amdgcn_mfma_f32_16x16x32_bf16(WLO, ah##AT, acc, 0, 0, 0); \
    acc = __builtin_amdgcn_mfma_f32_16x16x32_bf16(WHI, ah##AT, acc, 0, 0, 0); \
    const float e0 = acc[0] + BE4.x, e1 = acc[1] + BE4.y; \
    const float e2 = acc[2] + BE4.z, e3 = acc[3] + BE4.w; \
    p##AT##H += e0 * e0 + e1 * e1 + e2 * e2 + e3 * e3; }

#define TILE(T, H) { \
    const bf16x8 whi = *reinterpret_cast<const bf16x8*>(wefh + ((T * 64 + lane) << 3)); \
    const bf16x8 wlo = *reinterpret_cast<const bf16x8*>(wefl + ((T * 64 + lane) << 3)); \
    const float4 be4 = *reinterpret_cast<const float4*>(be + T * 16 + ((lane >> 4) << 2)); \
    AT_BODY(0, H, whi, wlo, be4) AT_BODY(1, H, whi, wlo, be4) \
    AT_BODY(2, H, whi, wlo, be4) AT_BODY(3, H, whi, wlo, be4) }

    TILE(0, 0) TILE(1, 0) TILE(2, 1) TILE(3, 1)
    TILE(4, 2) TILE(5, 2) TILE(6, 3) TILE(7, 3)
#undef TILE
#undef AT_BODY

#define RED(AT, H) \
    float r##AT##H = p##AT##H; \
    r##AT##H += __shfl_xor(r##AT##H, 16, 64); \
    r##AT##H += __shfl_xor(r##AT##H, 32, 64);
    RED(0, 0) RED(0, 1) RED(0, 2) RED(0, 3)
    RED(1, 0) RED(1, 1) RED(1, 2) RED(1, 3)
    RED(2, 0) RED(2, 1) RED(2, 2) RED(2, 3)
    RED(3, 0) RED(3, 1) RED(3, 2) RED(3, 3)
#undef RED

    const int at4 = lane >> 4;
#define SEL(H) ((at4 & 2) ? ((at4 & 1) ? r3##H : r2##H) : ((at4 & 1) ? r1##H : r0##H))
    const float w0 = SEL(0), w1 = SEL(1), w2 = SEL(2), w3 = SEL(3);
#undef SEL

    pay[pos] = make_float4(__int_as_float(dstn), w0 - w3, w1 - w3, w2 - w3);
}

// ---------------------------------------------------------------------------
// per-edge score+softmax+PV term (all shuffles stay inside the 32-lane group)
// ---------------------------------------------------------------------------
static __device__ __forceinline__ float edge_term(
    const uint4 u, const float4 pc, const float4 q4, const int h)
{
    const float scale = 0.17677669529663687f;  // 1/sqrt(32)
    const float k0 = __uint_as_float(u.x << 16);
    const float k1 = __uint_as_float(u.x & 0xffff0000u);
    const float k2 = __uint_as_float(u.y << 16);
    const float k3 = __uint_as_float(u.y & 0xffff0000u);
    float p =           q4.x * k0;
    p = fmaf(q4.y, k1, p); p = fmaf(q4.z, k2, p); p = fmaf(q4.w, k3, p);
    p += __shfl_xor(p, 1, 64);
    p += __shfl_xor(p, 2, 64);
    p += __shfl_xor(p, 4, 64);
    const float b  = __shfl_xor(p, 8, 64);
    const float e0 = (h & 1) ? b : p;
    const float e1 = (h & 1) ? p : b;
    const float o0 = __shfl_xor(e0, 16, 64);
    const float o1 = __shfl_xor(e1, 16, 64);
    const float qk0 = (h & 2) ? o0 : e0;
    const float qk1 = (h & 2) ? o1 : e1;
    const float qk2 = (h & 2) ? e0 : o0;
    const float qk3 = (h & 2) ? e1 : o1;

    const float s0 = (qk0 + pc.y) * scale;
    const float s1 = (qk1 + pc.z) * scale;
    const float s2 = (qk2 + pc.w) * scale;
    const float s3 = qk3 * scale;
    const float mx = fmaxf(fmaxf(s0, s1), fmaxf(s2, s3));
    const float a0 = __expf(s0 - mx), a1 = __expf(s1 - mx);
    const float a2 = __expf(s2 - mx), a3 = __expf(s3 - mx);
    const float inv = 1.f / (a0 + a1 + a2 + a3);
    const float p0 = __uint_as_float(u.z << 16);
    const float p1 = __uint_as_float(u.z & 0xffff0000u);
    const float p2 = __uint_as_float(u.w << 16);
    const float p3 = __uint_as_float(u.w & 0xffff0000u);
    return fmaf(a0, p0, fmaf(a1, p1, fmaf(a2, p2, a3 * p3))) * inv;
}

// ---------------------------------------------------------------------------
// Kernel D: fused score+softmax+aggregate, CSR order, 2-edge unrolled.
//   block = node n, 8 groups of 32 lanes; group = 2 edges/iter (MLP).
//   lane o: one 16B KPT gather per edge; 6-shuffle reduce+bcast; softmax; PV.
// ---------------------------------------------------------------------------
__global__ __launch_bounds__(256) void fused_gather_kernel(
    const int* __restrict__ off, const int* __restrict__ deg,
    const float4* __restrict__ pay,
    const float* __restrict__ Q, const unsigned short* __restrict__ KPTb,
    const float* __restrict__ bo, float* __restrict__ out)
{
    __shared__ float red[8][OUT_DIM];
    const int n = blockIdx.x;
    const int d = deg[n];
    const int start = off[n];
    const int tid = threadIdx.x;
    const int g = tid >> 5, o = tid & 31;
    const int h = o >> 3;

    const float4 q4 = *reinterpret_cast<const float4*>(Q + (size_t)n * HD + o * 4);

    float acc = 0.f;
    float4 pc0 = make_float4(0.f, 0.f, 0.f, 0.f);
    float4 pc1 = make_float4(0.f, 0.f, 0.f, 0.f);
    if (g < d)     pc0 = pay[start + g];
    if (g + 8 < d) pc1 = pay[start + g + 8];

    for (int i = g; i < d; i += 16) {
        float4 pn0 = make_float4(0.f, 0.f, 0.f, 0.f);
        float4 pn1 = make_float4(0.f, 0.f, 0.f, 0.f);
        if (i + 16 < d) pn0 = pay[start + i + 16];
        if (i + 24 < d) pn1 = pay[start + i + 24];

        const int dst0 = __float_as_int(pc0.x);
        const int dst1 = __float_as_int(pc1.x);   // row 0 if invalid (zero-init)
        const uint4 u0 = *reinterpret_cast<const uint4*>(KPTb + (size_t)dst0 * 256 + o * 8);
        const uint4 u1 = *reinterpret_cast<const uint4*>(KPTb + (size_t)dst1 * 256 + o * 8);

        acc += edge_term(u0, pc0, q4, h);
        if (i + 8 < d)                          // group-uniform branch
            acc += edge_term(u1, pc1, q4, h);

        pc0 = pn0; pc1 = pn1;
    }
    red[g][o] = acc;
    __syncthreads();
    if (tid < 32) {
        const float s = red[0][o] + red[1][o] + red[2][o] + red[3][o]
                      + red[4][o] + red[5][o] + red[6][o] + red[7][o];
        out[(size_t)n * OUT_DIM + o] = (d > 0) ? (s / (float)d + bo[o]) : 0.f;
    }
}

extern "C" void kernel_launch(void* const* d_in, const int* in_sizes, int n_in,
                              void* d_out, int out_size, void* d_ws, size_t ws_size,
                              hipStream_t stream)
{
    const float* x   = (const float*)d_in[0];
    const int*   ei  = (const int*)  d_in[1];
    const float* ea  = (const float*)d_in[2];
    const float* Wq  = (const float*)d_in[3];
    const float* bq  = (const float*)d_in[4];
    const float* Wk  = (const float*)d_in[5];
    const float* bk  = (const float*)d_in[6];
    const float* Wv  = (const float*)d_in[7];
    const float* bv  = (const float*)d_in[8];
    const float* We  = (const float*)d_in[9];
    const float* be  = (const float*)d_in[10];
    const float* Wo  = (const float*)d_in[11];
    const float* bo  = (const float*)d_in[12];
    float* out = (float*)d_out;

    // workspace layout (16B-aligned chunks)
    float*  Q    = (float*)d_ws;                          // NN*HD f32
    float4* pay  = (float4*)(Q + (size_t)NN * HD);        // NE_ float4
    unsigned short* KPTb = (unsigned short*)(pay + NE_);  // NN*256 bf16 (K|PT interleaved)
    float*  bp   = (float*)(KPTb + (size_t)NN * 256);     // HD f32
    unsigned short* wefh = (unsigned short*)(bp + HD);    // 4096
    unsigned short* wefl = wefh + 8 * 64 * 8;             // 4096
    unsigned short* wfh  = wefl + 8 * 64 * 8;             // 24*4*64*8 = 49152
    unsigned short* wfl  = wfh + 24 * 4 * 64 * 8;         // 49152
    int* rank = (int*)(wfl + 24 * 4 * 64 * 8);            // NE_
    int* deg  = rank + NE_;                               // NN
    int* off  = deg + NN;                                 // NN

    hipMemsetAsync(deg, 0, NN * sizeof(int), stream);

    prep_kernel<<<27 + HIST_BLKS, 256, 0, stream>>>(Wq, Wk, Wv, Wo, bv, We, ei,
                                                    wfh, wfl, wefh, wefl, bp,
                                                    deg, rank);
    scan_kernel<<<1, SCAN_T, 0, stream>>>(deg, off);
    mm_kernel<<<QKVP_BLKS + EE_BLKS, 256, 0, stream>>>(x, wfh, wfl, bq, bk, bp,
                                                       Q, KPTb, ea, wefh, wefl,
                                                       be, ei, off, rank, pay);
    fused_gather_kernel<<<NN, 256, 0, stream>>>(off, deg, pay, Q, KPTb, bo, out);
}

// Round 10
// 127.933 us; speedup vs baseline: 3.9997x; 1.0473x over previous
//
#include <hip/hip_runtime.h>

#define NN      10000
#define IN_DIM  128
#define E_DIM   32
#define NH      4
#define DH      32
#define HD      128   // NH*DH
#define NE_     640000
#define OUT_DIM 32
#define SCAN_T  1024
#define CHUNK   10    // SCAN_T*CHUNK >= NN
#define NTILES  (NN / 16)        // 625 node-tiles
#define NTASKS  (NTILES * 3)     // x 3 col-groups (Q, K, P)
#define QKVP_BLKS  469           // ceil(NTASKS/4)
#define HIST_BLKS  (NE_ / 256)   // 2500
#define EE_BLKS    (NE_ / 256)   // 2500

typedef __attribute__((ext_vector_type(8))) short bf16x8;
typedef __attribute__((ext_vector_type(4))) float f32x4;

static __device__ __forceinline__ unsigned short f32_to_bf16_rne(float f) {
    unsigned u = __float_as_uint(f);
    return (unsigned short)((u + 0x7fffu + ((u >> 16) & 1u)) >> 16);
}
static __device__ __forceinline__ float bf16_bits_to_f32(unsigned short h) {
    return __uint_as_float(((unsigned)h) << 16);
}
static __device__ __forceinline__ float blo(unsigned u) { return __uint_as_float(u << 16); }
static __device__ __forceinline__ float bhi(unsigned u) { return __uint_as_float(u & 0xffff0000u); }

// ---------------------------------------------------------------------------
// Kernel A (prep + hist, block-range dispatch; all parts independent):
//  blocks [0,24):   wfrag -- hi/lo A-fragments of [Wq|Wk|Wp], Wp inline
//  blocks [24,26):  wet   -- hi/lo A-fragments of We
//  block  26:       bp[flat] = sum_d bv[h*32+d]*Wo[..o],  flat = o*4+h
//  blocks [27,...): hist_rank -- deg histogram + per-edge rank
// ---------------------------------------------------------------------------
__global__ __launch_bounds__(256) void prep_kernel(
    const float* __restrict__ Wq, const float* __restrict__ Wk,
    const float* __restrict__ Wv, const float* __restrict__ Wo,
    const float* __restrict__ bv, const float* __restrict__ We,
    const int*   __restrict__ ei,
    unsigned short* __restrict__ wfh, unsigned short* __restrict__ wfl,
    unsigned short* __restrict__ wefh, unsigned short* __restrict__ wefl,
    float* __restrict__ bp,
    int* __restrict__ deg, int* __restrict__ rank)
{
    const int blk = blockIdx.x;
    const int t = threadIdx.x;

    if (blk < 24) {                         // ---- wfrag (6144 threads) ----
        const int tid = blk * 256 + t;      // (tt*4+s)*64 + l
        const int l = tid & 63;
        const int ts = tid >> 6;
        const int s = ts & 3, tt = ts >> 2; // tt 0..23
        const int col = (tt & 7) * 16 + (l & 15);
        if (tt < 16) {
            const float* __restrict__ W = (tt < 8) ? Wq : Wk;
            #pragma unroll
            for (int j = 0; j < 8; ++j) {
                const int k = s * 32 + (l >> 4) * 8 + j;
                const float w = W[k * HD + col];
                const unsigned short hi = f32_to_bf16_rne(w);
                wfh[tid * 8 + j] = hi;
                wfl[tid * 8 + j] = f32_to_bf16_rne(w - bf16_bits_to_f32(hi));
            }
        } else {                            // Wp inline
            const int h = col & 3, oo = col >> 2;
            #pragma unroll
            for (int j = 0; j < 8; ++j) {
                const int k = s * 32 + (l >> 4) * 8 + j;
                float acc = 0.f;
                #pragma unroll
                for (int d2 = 0; d2 < DH; ++d2)
                    acc = fmaf(Wv[k * HD + h * DH + d2],
                               Wo[(h * DH + d2) * OUT_DIM + oo], acc);
                const unsigned short hi = f32_to_bf16_rne(acc);
                wfh[tid * 8 + j] = hi;
                wfl[tid * 8 + j] = f32_to_bf16_rne(acc - bf16_bits_to_f32(hi));
            }
        }
    } else if (blk < 26) {                  // ---- wet (512 threads) ----
        const int tid = (blk - 24) * 256 + t;
        const int l = tid & 63, tt = tid >> 6;
        #pragma unroll
        for (int j = 0; j < 8; ++j) {
            const int k = (l >> 4) * 8 + j;
            const int d = tt * 16 + (l & 15);
            const float w = We[k * HD + d];
            const unsigned short hi = f32_to_bf16_rne(w);
            wefh[tid * 8 + j] = hi;
            wefl[tid * 8 + j] = f32_to_bf16_rne(w - bf16_bits_to_f32(hi));
        }
    } else if (blk == 26) {                 // ---- bp ----
        if (t < HD) {
            const int h = t & 3, oo = t >> 2;
            float b = 0.f;
            #pragma unroll
            for (int d2 = 0; d2 < DH; ++d2)
                b = fmaf(bv[h * DH + d2], Wo[(h * DH + d2) * OUT_DIM + oo], b);
            bp[t] = b;
        }
    } else {                                // ---- hist_rank ----
        const int e = (blk - 27) * 256 + t;
        rank[e] = atomicAdd(&deg[ei[e]], 1);
    }
}

// ---------------------------------------------------------------------------
// Kernel B: exclusive scan of deg -> off (shfl-based, 2 barriers)
// ---------------------------------------------------------------------------
__global__ __launch_bounds__(SCAN_T) void scan_kernel(
    const int* __restrict__ deg, int* __restrict__ off)
{
    __shared__ int wsum[16];
    const int t = threadIdx.x;
    const int lane = t & 63, w = t >> 6;
    const int base = t * CHUNK;
    int v[CHUNK];
    int sum = 0;
    #pragma unroll
    for (int i = 0; i < CHUNK; ++i) {
        const int idx = base + i;
        v[i] = (idx < NN) ? deg[idx] : 0;
        sum += v[i];
    }
    int incl = sum;
    #pragma unroll
    for (int dlt = 1; dlt < 64; dlt <<= 1) {
        const int nb = __shfl_up(incl, dlt, 64);
        if (lane >= dlt) incl += nb;
    }
    if (lane == 63) wsum[w] = incl;
    __syncthreads();
    if (w == 0) {
        const int val = (lane < 16) ? wsum[lane] : 0;
        int wi = val;
        #pragma unroll
        for (int dlt = 1; dlt < 16; dlt <<= 1) {
            const int nb = __shfl_up(wi, dlt, 64);
            if (lane >= dlt) wi += nb;
        }
        if (lane < 16) wsum[lane] = wi - val;   // exclusive wave prefix
    }
    __syncthreads();
    int run = wsum[w] + (incl - sum);
    #pragma unroll
    for (int i = 0; i < CHUNK; ++i) {
        const int idx = base + i;
        if (idx < NN) { off[idx] = run; run += v[i]; }
    }
}

// ---------------------------------------------------------------------------
// Kernel C (mm, block-range dispatch):
//  blocks [0,QKVP_BLKS):  node GEMM [Q|K|PT] = x @ [Wq|Wk|Wp] (+bias via MFMA
//    C-init). K/PT interleaved in KPTb rows (512B).
//  blocks [QKVP_BLKS,..): ee via split-We MFMA (be via C-init).
//    Epilogue: eev[e] = (dst, ee-deltas) COALESCED; ids[pos] = e -- the only
//    scatter is 4B into a 2.56MB table (fits per-XCD L2 -> write-merges).
//  All fragments/accumulators are named scalars (R6: arrays got LDS-promoted).
// ---------------------------------------------------------------------------
__global__ __launch_bounds__(256) void mm_kernel(
    const float* __restrict__ x,
    const unsigned short* __restrict__ wfh, const unsigned short* __restrict__ wfl,
    const float* __restrict__ bq, const float* __restrict__ bk,
    const float* __restrict__ bp,
    float* __restrict__ Q, unsigned short* __restrict__ KPTb,
    const float* __restrict__ ea,
    const unsigned short* __restrict__ wefh, const unsigned short* __restrict__ wefl,
    const float* __restrict__ be,
    const int* __restrict__ ei,
    const int* __restrict__ off, const int* __restrict__ rank,
    float4* __restrict__ eev, int* __restrict__ ids)
{
    const int lane = threadIdx.x & 63;
    const int wave = threadIdx.x >> 6;

    if (blockIdx.x < QKVP_BLKS) {
        // ------------------- qkvp GEMM -------------------
        const int task = blockIdx.x * 4 + wave;
        if (task >= NTASKS) return;
        const int nt = task / 3, cg = task - nt * 3;
        const int node = nt * 16 + (lane & 15);
        const int kc = lane >> 4;          // 0..3

        bf16x8 xh0, xl0, xh1, xl1, xh2, xl2, xh3, xl3;
#define SPL(VH, VL, I, VAL) { \
    const unsigned short hh = f32_to_bf16_rne(VAL); \
    VH[I] = (short)hh; VL[I] = (short)f32_to_bf16_rne((VAL) - bf16_bits_to_f32(hh)); }
#define LOAD_X(S, VH, VL) { \
    const float* xr = x + (size_t)node * IN_DIM + (S) * 32 + kc * 8; \
    const float4 a0 = *reinterpret_cast<const float4*>(xr); \
    const float4 a1 = *reinterpret_cast<const float4*>(xr + 4); \
    SPL(VH, VL, 0, a0.x) SPL(VH, VL, 1, a0.y) SPL(VH, VL, 2, a0.z) SPL(VH, VL, 3, a0.w) \
    SPL(VH, VL, 4, a1.x) SPL(VH, VL, 5, a1.y) SPL(VH, VL, 6, a1.z) SPL(VH, VL, 7, a1.w) }
        LOAD_X(0, xh0, xl0) LOAD_X(1, xh1, xl1) LOAD_X(2, xh2, xl2) LOAD_X(3, xh3, xl3)
#undef LOAD_X
#undef SPL

        const float* __restrict__ bb = (cg == 0) ? bq : (cg == 1) ? bk : bp;

#define KSTEP(S, FB, FB2, XH, XL) { \
    const bf16x8 wh = *reinterpret_cast<const bf16x8*>((FB)  + (S) * 64 * 8); \
    const bf16x8 wl = *reinterpret_cast<const bf16x8*>((FB2) + (S) * 64 * 8); \
    acc = __builtin_amdgcn_mfma_f32_16x16x32_bf16(wh, XH, acc, 0, 0, 0); \
    acc = __builtin_amdgcn_mfma_f32_16x16x32_bf16(wh, XL, acc, 0, 0, 0); \
    acc = __builtin_amdgcn_mfma_f32_16x16x32_bf16(wl, XH, acc, 0, 0, 0); }

#define TILE(TLOC) { \
    const unsigned short* fb  = wfh + ((((cg * 8 + TLOC) * 4) * 64 + lane) << 3); \
    const unsigned short* fb2 = wfl + ((((cg * 8 + TLOC) * 4) * 64 + lane) << 3); \
    const float4 b4 = *reinterpret_cast<const float4*>(bb + (TLOC) * 16 + (kc << 2)); \
    f32x4 acc = {b4.x, b4.y, b4.z, b4.w}; \
    KSTEP(0, fb, fb2, xh0, xl0) KSTEP(1, fb, fb2, xh1, xl1) \
    KSTEP(2, fb, fb2, xh2, xl2) KSTEP(3, fb, fb2, xh3, xl3) \
    const int j0 = (TLOC) * 16 + (kc << 2); \
    if (cg == 0) { \
        *reinterpret_cast<float4*>(Q + (size_t)node * HD + j0) = \
            make_float4(acc[0], acc[1], acc[2], acc[3]); \
    } else { \
        unsigned short* dp = KPTb + (size_t)node * 256 + j0 * 2 + ((cg == 1) ? 0 : 4); \
        *reinterpret_cast<ushort4*>(dp) = make_ushort4( \
            f32_to_bf16_rne(acc[0]), f32_to_bf16_rne(acc[1]), \
            f32_to_bf16_rne(acc[2]), f32_to_bf16_rne(acc[3])); \
    } }

        TILE(0) TILE(1) TILE(2) TILE(3) TILE(4) TILE(5) TILE(6) TILE(7)
#undef TILE
#undef KSTEP
        return;
    }

    // ------------------- ee (coalesced) + 4B id scatter -------------------
    const int base = (blockIdx.x - QKVP_BLKS) * 256 + wave * 64;  // 64 edges/wave

    const int src  = ei[base + lane];
    const int dstn = ei[NE_ + base + lane];
    const int pos  = off[src] + rank[base + lane];

    const int erow = lane & 15;
    const int kc = lane >> 4;          // k-chunk 0..3
    bf16x8 ah0, ah1, ah2, ah3;
#define LOAD_A(AT, VAR) { \
    const float* ar = ea + (size_t)(base + AT * 16 + erow) * E_DIM + kc * 8; \
    const float4 a0 = *reinterpret_cast<const float4*>(ar); \
    const float4 a1 = *reinterpret_cast<const float4*>(ar + 4); \
    VAR[0] = (short)f32_to_bf16_rne(a0.x); VAR[1] = (short)f32_to_bf16_rne(a0.y); \
    VAR[2] = (short)f32_to_bf16_rne(a0.z); VAR[3] = (short)f32_to_bf16_rne(a0.w); \
    VAR[4] = (short)f32_to_bf16_rne(a1.x); VAR[5] = (short)f32_to_bf16_rne(a1.y); \
    VAR[6] = (short)f32_to_bf16_rne(a1.z); VAR[7] = (short)f32_to_bf16_rne(a1.w); }
    LOAD_A(0, ah0) LOAD_A(1, ah1) LOAD_A(2, ah2) LOAD_A(3, ah3)
#undef LOAD_A

    float p00 = 0.f, p01 = 0.f, p02 = 0.f, p03 = 0.f;
    float p10 = 0.f, p11 = 0.f, p12 = 0.f, p13 = 0.f;
    float p20 = 0.f, p21 = 0.f, p22 = 0.f, p23 = 0.f;
    float p30 = 0.f, p31 = 0.f, p32 = 0.f, p33 = 0.f;

#define AT_BODY(AT, H, WHI, WLO, BE4) { \
    f32x4 acc = {BE4.x, BE4.y, BE4.z, BE4.w}; \
    acc = __builtin_amdgcn_mfma_f32_16x16x32_bf16(WLO, ah##AT, acc, 0, 0, 0); \
    acc = __builtin_amdgcn_mfma_f32_16x16x32_bf16(WHI, ah##AT, acc, 0, 0, 0); \
    p##AT##H = fmaf(acc[0], acc[0], fmaf(acc[1], acc[1], \
               fmaf(acc[2], acc[2], fmaf(acc[3], acc[3], p##AT##H)))); }

#define TILE(T, H) { \
    const bf16x8 whi = *reinterpret_cast<const bf16x8*>(wefh + ((T * 64 + lane) << 3)); \
    const bf16x8 wlo = *reinterpret_cast<const bf16x8*>(wefl + ((T * 64 + lane) << 3)); \
    const float4 be4 = *reinterpret_cast<const float4*>(be + T * 16 + ((lane >> 4) << 2)); \
    AT_BODY(0, H, whi, wlo, be4) AT_BODY(1, H, whi, wlo, be4) \
    AT_BODY(2, H, whi, wlo, be4) AT_BODY(3, H, whi, wlo, be4) }

    TILE(0, 0) TILE(1, 0) TILE(2, 1) TILE(3, 1)
    TILE(4, 2) TILE(5, 2) TILE(6, 3) TILE(7, 3)
#undef TILE
#undef AT_BODY

#define RED(AT, H) \
    float r##AT##H = p##AT##H; \
    r##AT##H += __shfl_xor(r##AT##H, 16, 64); \
    r##AT##H += __shfl_xor(r##AT##H, 32, 64);
    RED(0, 0) RED(0, 1) RED(0, 2) RED(0, 3)
    RED(1, 0) RED(1, 1) RED(1, 2) RED(1, 3)
    RED(2, 0) RED(2, 1) RED(2, 2) RED(2, 3)
    RED(3, 0) RED(3, 1) RED(3, 2) RED(3, 3)
#undef RED

    const int at4 = lane >> 4;
#define SEL(H) ((at4 & 2) ? ((at4 & 1) ? r3##H : r2##H) : ((at4 & 1) ? r1##H : r0##H))
    const float w0 = SEL(0), w1 = SEL(1), w2 = SEL(2), w3 = SEL(3);
#undef SEL

    eev[base + lane] = make_float4(__int_as_float(dstn), w0 - w3, w1 - w3, w2 - w3);
    ids[pos] = base + lane;
}

// ---------------------------------------------------------------------------
// Kernel D: fused score+softmax+aggregate, CSR order, 16 lanes per edge.
//   block = node n, 16 groups of 16 lanes; group = one edge/iter -> 4 edges
//   per wave-instruction (softmax amortized 4x vs 32-lane groups).
//   lane o16: dims o16*8..+7 (two uint4 KPT loads); emits out dims 2*o16,+1.
//   ids prefetched 2 iters ahead, eev payload 1 iter ahead.
// ---------------------------------------------------------------------------
__global__ __launch_bounds__(256) void fused_gather_kernel(
    const int* __restrict__ off, const int* __restrict__ deg,
    const int* __restrict__ ids, const float4* __restrict__ eev,
    const float* __restrict__ Q, const unsigned short* __restrict__ KPTb,
    const float* __restrict__ bo, float* __restrict__ out)
{
    __shared__ float red[16][OUT_DIM];
    const int n = blockIdx.x;
    const int d = deg[n];
    const int start = off[n];
    const int tid = threadIdx.x;
    const int g = tid >> 4;          // group 0..15
    const int o16 = tid & 15;        // lane in group
    const int h = o16 >> 2;
    const float scale = 0.17677669529663687f;  // 1/sqrt(32)

    const float* __restrict__ qrow = Q + (size_t)n * HD + o16 * 8;
    const float4 qa = *reinterpret_cast<const float4*>(qrow);
    const float4 qb = *reinterpret_cast<const float4*>(qrow + 4);

    float acc0 = 0.f, acc1 = 0.f;

    // pipeline: ids 2 ahead, payload 1 ahead
    float4 pc = make_float4(0.f, 0.f, 0.f, 0.f);
    int idn = 0;
    if (g < d)      pc  = eev[ids[start + g]];
    if (g + 16 < d) idn = ids[start + g + 16];

    for (int i = g; i < d; i += 16) {
        int idn2 = 0;
        if (i + 32 < d) idn2 = ids[start + i + 32];
        float4 pn = make_float4(0.f, 0.f, 0.f, 0.f);
        if (i + 16 < d) pn = eev[idn];

        const int dst = __float_as_int(pc.x);
        const unsigned short* __restrict__ kp = KPTb + (size_t)dst * 256 + o16 * 16;
        const uint4 u0 = *reinterpret_cast<const uint4*>(kp);
        const uint4 u1 = *reinterpret_cast<const uint4*>(kp + 8);

        float p =           qa.x * blo(u0.x);
        p = fmaf(qa.y, bhi(u0.x), p);
        p = fmaf(qa.z, blo(u0.y), p);
        p = fmaf(qa.w, bhi(u0.y), p);
        p = fmaf(qb.x, blo(u1.x), p);
        p = fmaf(qb.y, bhi(u1.x), p);
        p = fmaf(qb.z, blo(u1.y), p);
        p = fmaf(qb.w, bhi(u1.y), p);
        p += __shfl_xor(p, 1, 64);
        p += __shfl_xor(p, 2, 64);           // qk_h in each 4-lane cluster
        const float b  = __shfl_xor(p, 4, 64);
        const float e0 = (h & 1) ? b : p;
        const float e1 = (h & 1) ? p : b;
        const float o0 = __shfl_xor(e0, 8, 64);
        const float o1 = __shfl_xor(e1, 8, 64);
        const float qk0 = (h & 2) ? o0 : e0;
        const float qk1 = (h & 2) ? o1 : e1;
        const float qk2 = (h & 2) ? e0 : o0;
        const float qk3 = (h & 2) ? e1 : o1;

        const float s0 = (qk0 + pc.y) * scale;
        const float s1 = (qk1 + pc.z) * scale;
        const float s2 = (qk2 + pc.w) * scale;
        const float s3 = qk3 * scale;
        const float mx = fmaxf(fmaxf(s0, s1), fmaxf(s2, s3));
        const float a0 = __expf(s0 - mx), a1 = __expf(s1 - mx);
        const float a2 = __expf(s2 - mx), a3 = __expf(s3 - mx);
        const float inv = 1.f / (a0 + a1 + a2 + a3);

        float c0 =          a0 * blo(u0.z);
        c0 = fmaf(a1, bhi(u0.z), c0);
        c0 = fmaf(a2, blo(u0.w), c0);
        c0 = fmaf(a3, bhi(u0.w), c0);
        float c1 =          a0 * blo(u1.z);
        c1 = fmaf(a1, bhi(u1.z), c1);
        c1 = fmaf(a2, blo(u1.w), c1);
        c1 = fmaf(a3, bhi(u1.w), c1);
        acc0 = fmaf(c0, inv, acc0);
        acc1 = fmaf(c1, inv, acc1);

        pc = pn; idn = idn2;
    }
    red[g][o16 * 2]     = acc0;
    red[g][o16 * 2 + 1] = acc1;
    __syncthreads();
    if (tid < 32) {
        float s = 0.f;
        #pragma unroll
        for (int gg = 0; gg < 16; ++gg) s += red[gg][tid];
        out[(size_t)n * OUT_DIM + tid] = (d > 0) ? (s / (float)d + bo[tid]) : 0.f;
    }
}

extern "C" void kernel_launch(void* const* d_in, const int* in_sizes, int n_in,
                              void* d_out, int out_size, void* d_ws, size_t ws_size,
                              hipStream_t stream)
{
    const float* x   = (const float*)d_in[0];
    const int*   ei  = (const int*)  d_in[1];
    const float* ea  = (const float*)d_in[2];
    const float* Wq  = (const float*)d_in[3];
    const float* bq  = (const float*)d_in[4];
    const float* Wk  = (const float*)d_in[5];
    const float* bk  = (const float*)d_in[6];
    const float* Wv  = (const float*)d_in[7];
    const float* bv  = (const float*)d_in[8];
    const float* We  = (const float*)d_in[9];
    const float* be  = (const float*)d_in[10];
    const float* Wo  = (const float*)d_in[11];
    const float* bo  = (const float*)d_in[12];
    float* out = (float*)d_out;

    // workspace layout (16B-aligned chunks)
    float*  Q    = (float*)d_ws;                          // NN*HD f32
    float4* eev  = (float4*)(Q + (size_t)NN * HD);        // NE_ float4 (edge order)
    unsigned short* KPTb = (unsigned short*)(eev + NE_);  // NN*256 bf16 (K|PT interleaved)
    float*  bp   = (float*)(KPTb + (size_t)NN * 256);     // HD f32
    unsigned short* wefh = (unsigned short*)(bp + HD);    // 4096
    unsigned short* wefl = wefh + 8 * 64 * 8;             // 4096
    unsigned short* wfh  = wefl + 8 * 64 * 8;             // 24*4*64*8 = 49152
    unsigned short* wfl  = wfh + 24 * 4 * 64 * 8;         // 49152
    int* rank = (int*)(wfl + 24 * 4 * 64 * 8);            // NE_
    int* ids  = rank + NE_;                               // NE_ (CSR slot -> edge id)
    int* deg  = ids + NE_;                                // NN
    int* off  = deg + NN;                                 // NN

    hipMemsetAsync(deg, 0, NN * sizeof(int), stream);

    prep_kernel<<<27 + HIST_BLKS, 256, 0, stream>>>(Wq, Wk, Wv, Wo, bv, We, ei,
                                                    wfh, wfl, wefh, wefl, bp,
                                                    deg, rank);
    scan_kernel<<<1, SCAN_T, 0, stream>>>(deg, off);
    mm_kernel<<<QKVP_BLKS + EE_BLKS, 256, 0, stream>>>(x, wfh, wfl, bq, bk, bp,
                                                       Q, KPTb, ea, wefh, wefl,
                                                       be, ei, off, rank, eev, ids);
    fused_gather_kernel<<<NN, 256, 0, stream>>>(off, deg, ids, eev, Q, KPTb, bo, out);
}